// Round 8
// baseline (342.794 us; speedup 1.0000x reference)
//
#include <hip/hip_runtime.h>

// FFTConvNet: out[b,o] = IFFT2( M · sum_i X^[(b+8)%16, i] · W^[(o+32)%64, i] ) + bias[o]
// fftshift(no axes) shifts ALL dims -> batch roll 8, Cout roll 32; Cin rolls cancel.
// Disk mask fy^2+fx^2<=900. Half-spectrum: fy(t) in [0,30] (31), fx in [-30,30] (61), f2 = fxp*31+t.
// Pipeline: k0 (W^ bf16, frag-order) ; k12 (fwd DFT -> X2[bi][f2]) ; ktx (X2 -> X2T[f2][i*16+b]) ;
//   k3 (MFMA mix, reads X2T coalesced, writes F[f2][b][col] IN-PLACE over X2T) ;
//   ktf (F -> FT[bo][f2]) ; k45 (inverse, contiguous FT rows).
// k12 v4: 2048 blocks = (bi, t-half). Grid was the occupancy limit (1024 blocks = 4/CU fixed);
//   now 8 blocks/CU. Per thread: 2 freqs (te=16th+2tg, to=te+1). Cls = 4 planes x 516 float2
//   (16.5 KB): plane stride 516 -> r-planes on distinct bank-quads; slot = tloc^(xg&15).
// ws (62 MB): WtB u32 [0, 7745536) ; A = X2 / FT float [7745536, +3872768) ;
//             B = X2T / F float [11618304, +3872768).

#define PI2_128 0.04908738521234052f  // 2*pi/128
#define NF 1891

typedef __attribute__((ext_vector_type(8))) short bf16x8;
typedef __attribute__((ext_vector_type(4))) float f32x4;

// fxp list ordered by class r=(fxp+2)&3 (= fx mod 4): c0(15), c1(15), c2(16), c3(15), 3 dummies.
__device__ const int k_flist[64] = {
    2, 6, 10, 14, 18, 22, 26, 30, 34, 38, 42, 46, 50, 54, 58,
    3, 7, 11, 15, 19, 23, 27, 31, 35, 39, 43, 47, 51, 55, 59,
    0, 4, 8, 12, 16, 20, 24, 28, 32, 36, 40, 44, 48, 52, 56, 60,
    1, 5, 9, 13, 17, 21, 25, 29, 33, 37, 41, 45, 49, 53, 57,
    0, 0, 0};

__device__ inline unsigned bf16_rne(float v) {
  unsigned u = __float_as_uint(v);
  return (u + 0x7FFFu + ((u >> 16) & 1u)) >> 16;
}

__device__ inline bf16x8 mk_bf16x8(unsigned a, unsigned b, unsigned c, unsigned d) {
  union { unsigned u[4]; bf16x8 v; } x;
  x.u[0] = a; x.u[1] = b; x.u[2] = c; x.u[3] = d;
  return x.v;
}

// ---------------- K0: W^ precompute (bf16), separable 3x3 twiddles ----------------
__global__ __launch_bounds__(256) void k0_what(const float* __restrict__ w,
                                               unsigned* __restrict__ Wt) {
  const int tid = threadIdx.x;
  const int fxp = blockIdx.x >> 4;  // 0..60
  const int ig = blockIdx.x & 15;
  const int il = tid & 3;
  const int o = ((tid >> 5) << 3) | ((tid >> 2) & 7);
  const int i = ig * 4 + il;
  const int op = (o + 32) & 63;
  const float* wp = w + (size_t)(op * 64 + i) * 9;
  float w9[9];
#pragma unroll
  for (int k = 0; k < 9; ++k) w9[k] = wp[k];

  const float fx = (float)(fxp - 30);
  float sn, cs;
  __sincosf(fx * PI2_128, &sn, &cs);
  const float e1x = cs, e1y = -sn;
  const float e2x = e1x * e1x - e1y * e1y, e2y = 2.f * e1x * e1y;
  float rxr[3], rxi[3];
#pragma unroll
  for (int ky = 0; ky < 3; ++ky) {
    rxr[ky] = w9[ky * 3] + w9[ky * 3 + 1] * e1x + w9[ky * 3 + 2] * e2x;
    rxi[ky] = w9[ky * 3 + 1] * e1y + w9[ky * 3 + 2] * e2y;
  }
  float pyx = 1.f, pyy = 0.f;
  const float stx = 0.9987954562f, sty = -0.04906767433f;
  unsigned* Wb = Wt + (size_t)(fxp * 31) * 4096 + (o >> 3) * 512 + (i >> 4) * 128 +
                 (((i >> 2) & 3) * 8 + (o & 7)) * 4 + (i & 3);
  for (int fy = 0; fy < 31; ++fy) {
    float p2x = pyx * pyx - pyy * pyy, p2y = 2.f * pyx * pyy;
    float Wre = rxr[0] + (rxr[1] * pyx - rxi[1] * pyy) + (rxr[2] * p2x - rxi[2] * p2y);
    float Wim = rxi[0] + (rxr[1] * pyy + rxi[1] * pyx) + (rxr[2] * p2y + rxi[2] * p2x);
    Wb[(size_t)fy * 4096] = bf16_rne(Wre) | (bf16_rne(Wim) << 16);
    float nx = pyx * stx - pyy * sty;
    pyy = pyx * sty + pyy * stx;
    pyx = nx;
  }
}

// ---------------- K12: fused forward DFT (radix-4 folded both axes) ----------------
// v4: block = (bi, t-half). Phase A: each thread 2 freqs (te even, to odd) over its half.
// Cls[r*516 + x*16 + s], s = tloc ^ (x&15); tloc = t - 16*th in [0,16).
__global__ __launch_bounds__(256) void k12_fwd(const float* __restrict__ x,
                                               float* __restrict__ X2) {
  __shared__ __align__(16) float2 Cls[2064];  // 16512 B
  const int bi = blockIdx.x >> 1;
  const int th = blockIdx.x & 1;
  const int tid = threadIdx.x;
  const float* img = x + (size_t)bi * 16384;

  const int tg = tid >> 5;  // 0..7
  const int xg = tid & 31;

  // Phase A: y-DFT, radix-4 fold over y; freqs te = 16*th + 2*tg, to = te+1.
  {
    const int te = 16 * th + 2 * tg;
    const int to = te + 1;
    const float sgn = (tg & 1) ? 1.f : -1.f;  // to%4==3 -> +, ==1 -> -  (16th = 0 mod 4)
    const bool e_hi = (tg & 1) != 0;          // te%4==2 -> use a1, else a0
    float stcE, stsE, stcO, stsO;
    __sincosf((float)te * PI2_128, &stsE, &stcE);
    __sincosf((float)to * PI2_128, &stsO, &stcO);
    float pcE = 1.f, psE = 0.f, pcO = 1.f, psO = 0.f;
    float arE[4] = {0.f, 0.f, 0.f, 0.f}, aiE[4] = {0.f, 0.f, 0.f, 0.f};
    float arO[4] = {0.f, 0.f, 0.f, 0.f}, aiO[4] = {0.f, 0.f, 0.f, 0.f};
    for (int y = 0; y < 32; ++y) {
      float v[4][4];
#pragma unroll
      for (int k = 0; k < 4; ++k)
#pragma unroll
        for (int m = 0; m < 4; ++m) v[k][m] = img[(y + 32 * k) * 128 + xg + 32 * m];
#pragma unroll
      for (int m = 0; m < 4; ++m) {
        float s = v[0][m] + v[2][m], d = v[0][m] - v[2][m];
        float s2 = v[1][m] + v[3][m], d2 = (v[1][m] - v[3][m]) * sgn;
        float a0 = s + s2, a1 = s - s2;
        float ae = e_hi ? a1 : a0;
        arE[m] += ae * pcE;
        aiE[m] -= ae * psE;
        arO[m] += d * pcO + d2 * psO;
        aiO[m] += -d * psO + d2 * pcO;
      }
      {
        float c = pcE, s = psE;
        pcE = c * stcE - s * stsE;
        psE = s * stcE + c * stsE;
      }
      {
        float c = pcO, s = psO;
        pcO = c * stcO - s * stsO;
        psO = s * stcO + c * stsO;
      }
    }
    // In-register x-butterfly; write 4 class planes for both freqs.
#pragma unroll
    for (int f = 0; f < 2; ++f) {
      const float* ar_ = f ? arO : arE;
      const float* ai_ = f ? aiO : aiE;
      const int tloc = 2 * tg + f;
      float Ar = ar_[0] + ar_[2], Ai = ai_[0] + ai_[2];
      float Br = ar_[0] - ar_[2], Bi = ai_[0] - ai_[2];
      float Cr = ar_[1] + ar_[3], Ci = ai_[1] + ai_[3];
      float Dr = ar_[1] - ar_[3], Di = ai_[1] - ai_[3];
      const int s = tloc ^ (xg & 15);
      const int rowb = xg * 16 + s;
      Cls[0 * 516 + rowb] = make_float2(Ar + Cr, Ai + Ci);  // r=0: A+C
      Cls[1 * 516 + rowb] = make_float2(Br + Di, Bi - Dr);  // r=1: B-iD
      Cls[2 * 516 + rowb] = make_float2(Ar - Cr, Ai - Ci);  // r=2: A-C
      Cls[3 * 516 + rowb] = make_float2(Br - Di, Bi + Dr);  // r=3: B+iD
    }
  }
  __syncthreads();

  // Phase B: x-DFT on folded planes + disk mask. 1 fxp per thread, 4 t's of this half.
  {
    const int tq = (tid >> 5) & 3;
    const int ub = tid >> 7;
    const int fxg = tid & 31;
    const int li = 2 * fxg + ub;
    const int fxp = k_flist[li];
    const int r = (fxp + 2) & 3;
    float stc2, sts2;
    __sincosf((float)(fxp - 30) * PI2_128, &sts2, &stc2);
    float pc2 = 1.f, ps2 = 0.f;
    float accr[4] = {0.f, 0.f, 0.f, 0.f}, acci[4] = {0.f, 0.f, 0.f, 0.f};
    const int ts4 = 4 * tq;
    for (int xx = 0; xx < 32; ++xx) {
      const float2* bp = Cls + r * 516 + xx * 16;
      const int s0 = ts4 ^ (xx & 15);
      float2 p0 = bp[s0];
      float2 p1 = bp[s0 ^ 1];
      float2 p2 = bp[s0 ^ 2];
      float2 p3 = bp[s0 ^ 3];
      float zr[4] = {p0.x, p1.x, p2.x, p3.x};
      float zi[4] = {p0.y, p1.y, p2.y, p3.y};
      float c = pc2, s = ps2;
#pragma unroll
      for (int tt = 0; tt < 4; ++tt) {
        accr[tt] += zr[tt] * c + zi[tt] * s;
        acci[tt] += zi[tt] * c - zr[tt] * s;
      }
      pc2 = c * stc2 - s * sts2;
      ps2 = s * stc2 + c * sts2;
    }
    if (li < 61) {
      float2* X2c = (float2*)X2 + (size_t)bi * NF;
      const int fx = fxp - 30;
#pragma unroll
      for (int tt = 0; tt < 4; ++tt) {
        int t = 16 * th + ts4 + tt;
        if (t > 30) continue;
        bool keep = (t * t + fx * fx) <= 900;
        X2c[fxp * 31 + t] = keep ? make_float2(accr[tt], acci[tt]) : make_float2(0.f, 0.f);
      }
    }
  }
}

// ---------------- KTX: X2[bi][f2] -> X2T[f2][i*16+b]  (64x64 float2 LDS tiles) ------
__global__ __launch_bounds__(256) void ktx(const float2* __restrict__ X2,
                                           float2* __restrict__ X2T) {
  __shared__ __align__(16) float2 Ld[4096];
  const int tid = threadIdx.x;
  const int tf = blockIdx.x % 30;  // f2 tile
  const int tc = blockIdx.x / 30;  // out-col tile: i0 = tc*4
  const int f2_0 = tf * 64;
  const int lo = tid & 63, hi = tid >> 6;
#pragma unroll
  for (int k = 0; k < 16; ++k) {
    int c = k * 4 + hi;  // local out-col: c = (i-i0)*16 + b
    int bi = (c & 15) * 64 + tc * 4 + (c >> 4);
    int f2 = f2_0 + lo;
    float2 v = (f2 < NF) ? X2[(size_t)bi * NF + f2] : make_float2(0.f, 0.f);
    Ld[(c << 6) | (lo ^ c)] = v;  // XOR-swizzled: conflict-free both phases
  }
  __syncthreads();
#pragma unroll
  for (int k = 0; k < 16; ++k) {
    int fr = k * 4 + hi;
    int f2 = f2_0 + fr;
    if (f2 < NF) X2T[(size_t)f2 * 1024 + tc * 64 + lo] = Ld[(lo << 6) | (fr ^ lo)];
  }
}

// ---------------- K3: per-frequency channel mix via MFMA (bf16, X split hi/lo) ----
__global__ __launch_bounds__(256) void k3_mfma(const float* X2T,
                                               const unsigned* __restrict__ WtB,
                                               float* F) {
  // bijective XCD-chunked blockIdx swizzle (m204 form)
  const int nwg = (int)gridDim.x;
  const int orig = (int)blockIdx.x;
  const int xcd = orig & 7;
  const int q = nwg >> 3, r = nwg & 7;
  const int blk = (xcd < r ? xcd * (q + 1) : r * (q + 1) + (xcd - r) * q) + (orig >> 3);

  const int tid = (int)threadIdx.x;
  const int wv = tid >> 6;
  const int g = blk * 4 + wv;
  const int f2v = g >> 1;
  const bool valid = f2v < NF;
  const int f2 = valid ? f2v : NF - 1;  // clamp keeps reads in the block's own rows
  const int half = g & 1;
  const int lane = tid & 63;
  const int m = lane & 15;   // A-row (output batch) == B-col-within-tile
  const int lg = lane >> 4;  // k lane-group
  const int bs = (m + 8) & 15;
  const int co = m & 1;      // re/im column parity

  // ---- A: gather X2T row f2 (coalesced); i = ks*16 + lg*4 + t ----
  float2 xv[4][4];
  const float2* Xc = (const float2*)X2T;
#pragma unroll
  for (int ks = 0; ks < 4; ++ks)
#pragma unroll
    for (int t = 0; t < 4; ++t)
      xv[ks][t] = Xc[(size_t)f2 * 1024 + (ks * 16 + lg * 4 + t) * 16 + bs];

  __syncthreads();  // all waves done reading their rows before any in-place store

  unsigned ahi[4][4], alo[4][4];
#pragma unroll
  for (int ks = 0; ks < 4; ++ks) {
#pragma unroll
    for (int t = 0; t < 4; ++t) {
      float xr = xv[ks][t].x, xi = xv[ks][t].y;
      unsigned hr = bf16_rne(xr), hi2 = bf16_rne(xi);
      float lr = xr - __uint_as_float(hr << 16);
      float li = xi - __uint_as_float(hi2 << 16);
      ahi[ks][t] = hr | (hi2 << 16);
      alo[ks][t] = bf16_rne(lr) | (bf16_rne(li) << 16);
    }
  }

  f32x4 acc[4];
#pragma unroll
  for (int nt = 0; nt < 4; ++nt) acc[nt] = {0.f, 0.f, 0.f, 0.f};

  const unsigned* Wb =
      WtB + (size_t)f2 * 4096 + half * 2048 + (lg * 8 + (m >> 1)) * 4;
#pragma unroll
  for (int ks = 0; ks < 4; ++ks) {
    bf16x8 bfr[4];
#pragma unroll
    for (int nt = 0; nt < 4; ++nt) {
      uint4 wq = *(const uint4*)(Wb + nt * 512 + ks * 128);
      unsigned b0, b1, b2, b3;
      if (co) {  // odd col: (Wi, Wr) = rot16(w)
        b0 = (wq.x >> 16) | (wq.x << 16);
        b1 = (wq.y >> 16) | (wq.y << 16);
        b2 = (wq.z >> 16) | (wq.z << 16);
        b3 = (wq.w >> 16) | (wq.w << 16);
      } else {   // even col: (Wr, -Wi) = w ^ signbit(hi)
        b0 = wq.x ^ 0x80000000u;
        b1 = wq.y ^ 0x80000000u;
        b2 = wq.z ^ 0x80000000u;
        b3 = wq.w ^ 0x80000000u;
      }
      bfr[nt] = mk_bf16x8(b0, b1, b2, b3);
    }
    bf16x8 ah = mk_bf16x8(ahi[ks][0], ahi[ks][1], ahi[ks][2], ahi[ks][3]);
    bf16x8 al = mk_bf16x8(alo[ks][0], alo[ks][1], alo[ks][2], alo[ks][3]);
#pragma unroll
    for (int nt = 0; nt < 4; ++nt)
      acc[nt] = __builtin_amdgcn_mfma_f32_16x16x32_bf16(ah, bfr[nt], acc[nt], 0, 0, 0);
#pragma unroll
    for (int nt = 0; nt < 4; ++nt)
      acc[nt] = __builtin_amdgcn_mfma_f32_16x16x32_bf16(al, bfr[nt], acc[nt], 0, 0, 0);
  }

  if (valid) {
    float* Fo = F + (size_t)f2 * 2048 + half * 64 + m;
#pragma unroll
    for (int nt = 0; nt < 4; ++nt)
#pragma unroll
      for (int rr = 0; rr < 4; ++rr)
        Fo[(lg * 4 + rr) * 128 + nt * 16] = acc[nt][rr];
  }
}

// ---------------- KTF: F[f2][bo] -> FT[bo][f2]  (64x64 float2 LDS tiles) -----------
__global__ __launch_bounds__(256) void ktf(const float2* __restrict__ F2,
                                           float2* __restrict__ FT) {
  __shared__ __align__(16) float2 Ld[4096];
  const int tid = threadIdx.x;
  const int tf = blockIdx.x % 30;
  const int tc = blockIdx.x / 30;
  const int f2_0 = tf * 64, c0 = tc * 64;
  const int lo = tid & 63, hi = tid >> 6;
#pragma unroll
  for (int k = 0; k < 16; ++k) {
    int fr = k * 4 + hi;
    int f2 = f2_0 + fr;
    float2 v = (f2 < NF) ? F2[(size_t)f2 * 1024 + c0 + lo] : make_float2(0.f, 0.f);
    Ld[(fr << 6) | (lo ^ fr)] = v;
  }
  __syncthreads();
#pragma unroll
  for (int k = 0; k < 16; ++k) {
    int cc = k * 4 + hi;
    int f2 = f2_0 + lo;
    if (f2 < NF) FT[(size_t)(c0 + cc) * NF + f2] = Ld[(lo << 6) | (cc ^ lo)];
  }
}

// ---------------- K45: inverse (radix-4 fold in x, parity fold in y) + bias ----------------
__global__ __launch_bounds__(256) void k45_out(const float* __restrict__ FT,
                                               const float* __restrict__ bias,
                                               float* __restrict__ out) {
  __shared__ __align__(16) float2 tw[128];  // e^{+2pi i m/128}
  __shared__ __align__(16) float U[61 * 132];
  __shared__ __align__(16) float TF[3904];  // union: Fl (phase<=1), then T
  const int b = blockIdx.x >> 6;
  const int o = blockIdx.x & 63;
  const int tid = threadIdx.x;
  float2* Fl = (float2*)TF;
  // FT layout [bo][NF] -> contiguous row load.
  const float2* Fc = (const float2*)FT + (size_t)(b * 64 + o) * NF;
  if (tid < 128) {
    float sv, cv;
    __sincosf((float)tid * PI2_128, &sv, &cv);
    tw[tid] = make_float2(cv, sv);
  }
  for (int j = tid; j < NF; j += 256) Fl[j] = Fc[j];
  __syncthreads();

  // Phase 1: inverse-x with output fold H(x+32k) = sum_r i^{rk} S_r
  {
    const int fy = tid & 31;
    const int xg = tid >> 3 >> 2;  // tid>>5: 0..7
    if (fy < 31) {
      float Sr[4][4] = {{0.f}}, Si[4][4] = {{0.f}};  // [r][j]
      float pr[4], pi[4], cr[4], ci[4];
#pragma unroll
      for (int j = 0; j < 4; ++j) {
        int xj = 4 * xg + j;
        float2 st = tw[xj];
        cr[j] = st.x;
        ci[j] = st.y;
        float2 p0 = tw[(-30 * xj) & 127];
        pr[j] = p0.x;
        pi[j] = p0.y;
      }
      const float2* Frow = Fl + fy;
      for (int f4 = 0; f4 < 60; f4 += 4) {
#pragma unroll
        for (int ss = 0; ss < 4; ++ss) {
          const int r = (ss + 2) & 3;  // fxp class pattern 2,3,0,1
          float2 fv = Frow[(f4 + ss) * 31];
#pragma unroll
          for (int j = 0; j < 4; ++j) {
            Sr[r][j] += fv.x * pr[j] - fv.y * pi[j];
            Si[r][j] += fv.x * pi[j] + fv.y * pr[j];
            float np = pr[j] * cr[j] - pi[j] * ci[j];
            pi[j] = pi[j] * cr[j] + pr[j] * ci[j];
            pr[j] = np;
          }
        }
      }
      {  // fxp = 60, class 2
        float2 fv = Frow[60 * 31];
#pragma unroll
        for (int j = 0; j < 4; ++j) {
          Sr[2][j] += fv.x * pr[j] - fv.y * pi[j];
          Si[2][j] += fv.x * pi[j] + fv.y * pr[j];
        }
      }
#pragma unroll
      for (int j = 0; j < 4; ++j) {
        int xj = 4 * xg + j;
        float Er = Sr[0][j] + Sr[2][j], Ei = Si[0][j] + Si[2][j];
        float Fr = Sr[0][j] - Sr[2][j], Fi = Si[0][j] - Si[2][j];
        float Gr = Sr[1][j] + Sr[3][j], Gi = Si[1][j] + Si[3][j];
        float Hr = Sr[1][j] - Sr[3][j], Hi = Si[1][j] - Si[3][j];
        U[fy * 132 + xj] = Er + Gr;
        U[fy * 132 + xj + 32] = Fr - Hi;   // F4 + iH
        U[fy * 132 + xj + 64] = Er - Gr;
        U[fy * 132 + xj + 96] = Fr + Hi;   // F4 - iH
        if (fy >= 1) {
          U[(30 + fy) * 132 + xj] = Ei + Gi;
          U[(30 + fy) * 132 + xj + 32] = Fi + Hr;
          U[(30 + fy) * 132 + xj + 64] = Ei - Gi;
          U[(30 + fy) * 132 + xj + 96] = Fi - Hr;
        }
      }
    }
  }
  __syncthreads();
  // Build T[c][y] (y<64) over Fl's dead storage.
  {
    const float sc1 = 1.f / 16384.f;
    float* T = TF;
    for (int j = tid; j < 61 * 64; j += 256) {
      int c = j >> 6, y = j & 63;
      float val;
      if (c == 0) val = sc1;
      else if (c <= 30) val = 2.f * sc1 * tw[(c * y) & 127].x;
      else val = -2.f * sc1 * tw[((c - 30) * y) & 127].y;
      T[j] = val;
    }
  }
  __syncthreads();
  // Phase 2: inverse-y with parity fold (even c -> P, odd c -> Q); out[y]=P+Q, out[y+64]=P-Q
  {
    const float* T = TF;
    const int yg = tid >> 5;
    const int xg = tid & 31;
    const int y0 = yg * 8, x0 = xg * 4;
    float Pa[8][4] = {{0.f}}, Qa[8][4] = {{0.f}};
    for (int c = 0; c < 60; c += 2) {
      float tf0[8], tf1[8], uf0[4], uf1[4];
      *(float4*)&tf0[0] = *(const float4*)(&T[c * 64 + y0]);
      *(float4*)&tf0[4] = *(const float4*)(&T[c * 64 + y0 + 4]);
      *(float4*)&tf1[0] = *(const float4*)(&T[(c + 1) * 64 + y0]);
      *(float4*)&tf1[4] = *(const float4*)(&T[(c + 1) * 64 + y0 + 4]);
      *(float4*)&uf0[0] = *(const float4*)(&U[c * 132 + x0]);
      *(float4*)&uf1[0] = *(const float4*)(&U[(c + 1) * 132 + x0]);
#pragma unroll
      for (int jy = 0; jy < 8; ++jy)
#pragma unroll
        for (int jx = 0; jx < 4; ++jx) {
          Pa[jy][jx] += tf0[jy] * uf0[jx];
          Qa[jy][jx] += tf1[jy] * uf1[jx];
        }
    }
    {  // c = 60 (even -> P)
      float tf0[8], uf0[4];
      *(float4*)&tf0[0] = *(const float4*)(&T[60 * 64 + y0]);
      *(float4*)&tf0[4] = *(const float4*)(&T[60 * 64 + y0 + 4]);
      *(float4*)&uf0[0] = *(const float4*)(&U[60 * 132 + x0]);
#pragma unroll
      for (int jy = 0; jy < 8; ++jy)
#pragma unroll
        for (int jx = 0; jx < 4; ++jx) Pa[jy][jx] += tf0[jy] * uf0[jx];
    }
    const float bo_ = bias[o];
    float* op = out + (size_t)(b * 64 + o) * 16384;
#pragma unroll
    for (int jy = 0; jy < 8; ++jy) {
      float4 lo, hi;
      lo.x = Pa[jy][0] + Qa[jy][0] + bo_;
      lo.y = Pa[jy][1] + Qa[jy][1] + bo_;
      lo.z = Pa[jy][2] + Qa[jy][2] + bo_;
      lo.w = Pa[jy][3] + Qa[jy][3] + bo_;
      hi.x = Pa[jy][0] - Qa[jy][0] + bo_;
      hi.y = Pa[jy][1] - Qa[jy][1] + bo_;
      hi.z = Pa[jy][2] - Qa[jy][2] + bo_;
      hi.w = Pa[jy][3] - Qa[jy][3] + bo_;
      *(float4*)(op + (y0 + jy) * 128 + x0) = lo;
      *(float4*)(op + (y0 + jy + 64) * 128 + x0) = hi;
    }
  }
}

extern "C" void kernel_launch(void* const* d_in, const int* in_sizes, int n_in,
                              void* d_out, int out_size, void* d_ws, size_t ws_size,
                              hipStream_t stream) {
  (void)in_sizes; (void)n_in; (void)out_size; (void)ws_size;
  const float* x = (const float*)d_in[0];
  const float* w = (const float*)d_in[1];
  const float* bias = (const float*)d_in[2];
  float* out = (float*)d_out;

  unsigned* Wt = (unsigned*)d_ws;
  float* A = (float*)d_ws + 7745536;    // X2, later FT
  float* B = (float*)d_ws + 11618304;   // X2T, in-place F

  k0_what<<<976, 256, 0, stream>>>(w, Wt);
  k12_fwd<<<2048, 256, 0, stream>>>(x, A);
  ktx<<<480, 256, 0, stream>>>((const float2*)A, (float2*)B);
  k3_mfma<<<946, 256, 0, stream>>>(B, Wt, B);
  ktf<<<480, 256, 0, stream>>>((const float2*)B, (float2*)A);
  k45_out<<<1024, 256, 0, stream>>>(A, bias, out);
}

// Round 9
// 225.319 us; speedup vs baseline: 1.5214x; 1.5214x over previous
//
#include <hip/hip_runtime.h>

// FFTConvNet: out[b,o] = IFFT2( M · sum_i X^[(b+8)%16, i] · W^[(o+32)%64, i] ) + bias[o]
// fftshift(no axes) shifts ALL dims -> batch roll 8, Cout roll 32; Cin rolls cancel.
// Disk mask fy^2+fx^2<=900. Half-spectrum: fy(t) in [0,30] (31), fx in [-30,30] (61), f2 = fxp*31+t.
// Pipeline: k0 (W^ bf16, frag-order) ; k12 (fwd DFT -> X2[bi][f2]) ; ktx (X2 -> X2T[f2][i*16+b]) ;
//   k3 (MFMA mix, reads X2T coalesced, writes F[f2][b][col] IN-PLACE over X2T) ;
//   ktf (F -> FT[bo][f2]) ; k45 (inverse, contiguous FT rows).
// k12 v3: Phase A = v1 (direct VMEM, reg accum); Cls = 4 planes x 1024 float2 = 32 KB EXACT.
//   Conflicts killed by XOR swizzle slot = t ^ x ^ r. NOTE (R8 post-mortem): k12 is grid-capped
//   at 4 blocks/CU; t-half grid split regressed 3x (VGPR 148, 2x image fetch). ~67us is this
//   structure's floor.
// ws (62 MB): WtB u32 [0, 7745536) ; A = X2 / FT float [7745536, +3872768) ;
//             B = X2T / F float [11618304, +3872768).

#define PI2_128 0.04908738521234052f  // 2*pi/128
#define NF 1891

typedef __attribute__((ext_vector_type(8))) short bf16x8;
typedef __attribute__((ext_vector_type(4))) float f32x4;

// fxp list ordered by class r=(fxp+2)&3 (= fx mod 4): c0(15), c1(15), c2(16), c3(15), 3 dummies.
__device__ const int k_flist[64] = {
    2, 6, 10, 14, 18, 22, 26, 30, 34, 38, 42, 46, 50, 54, 58,
    3, 7, 11, 15, 19, 23, 27, 31, 35, 39, 43, 47, 51, 55, 59,
    0, 4, 8, 12, 16, 20, 24, 28, 32, 36, 40, 44, 48, 52, 56, 60,
    1, 5, 9, 13, 17, 21, 25, 29, 33, 37, 41, 45, 49, 53, 57,
    0, 0, 0};

__device__ inline unsigned bf16_rne(float v) {
  unsigned u = __float_as_uint(v);
  return (u + 0x7FFFu + ((u >> 16) & 1u)) >> 16;
}

__device__ inline bf16x8 mk_bf16x8(unsigned a, unsigned b, unsigned c, unsigned d) {
  union { unsigned u[4]; bf16x8 v; } x;
  x.u[0] = a; x.u[1] = b; x.u[2] = c; x.u[3] = d;
  return x.v;
}

// ---------------- K0: W^ precompute (bf16), separable 3x3 twiddles ----------------
__global__ __launch_bounds__(256) void k0_what(const float* __restrict__ w,
                                               unsigned* __restrict__ Wt) {
  const int tid = threadIdx.x;
  const int fxp = blockIdx.x >> 4;  // 0..60
  const int ig = blockIdx.x & 15;
  const int il = tid & 3;
  const int o = ((tid >> 5) << 3) | ((tid >> 2) & 7);
  const int i = ig * 4 + il;
  const int op = (o + 32) & 63;
  const float* wp = w + (size_t)(op * 64 + i) * 9;
  float w9[9];
#pragma unroll
  for (int k = 0; k < 9; ++k) w9[k] = wp[k];

  const float fx = (float)(fxp - 30);
  float sn, cs;
  __sincosf(fx * PI2_128, &sn, &cs);
  const float e1x = cs, e1y = -sn;
  const float e2x = e1x * e1x - e1y * e1y, e2y = 2.f * e1x * e1y;
  float rxr[3], rxi[3];
#pragma unroll
  for (int ky = 0; ky < 3; ++ky) {
    rxr[ky] = w9[ky * 3] + w9[ky * 3 + 1] * e1x + w9[ky * 3 + 2] * e2x;
    rxi[ky] = w9[ky * 3 + 1] * e1y + w9[ky * 3 + 2] * e2y;
  }
  float pyx = 1.f, pyy = 0.f;
  const float stx = 0.9987954562f, sty = -0.04906767433f;
  unsigned* Wb = Wt + (size_t)(fxp * 31) * 4096 + (o >> 3) * 512 + (i >> 4) * 128 +
                 (((i >> 2) & 3) * 8 + (o & 7)) * 4 + (i & 3);
  for (int fy = 0; fy < 31; ++fy) {
    float p2x = pyx * pyx - pyy * pyy, p2y = 2.f * pyx * pyy;
    float Wre = rxr[0] + (rxr[1] * pyx - rxi[1] * pyy) + (rxr[2] * p2x - rxi[2] * p2y);
    float Wim = rxi[0] + (rxr[1] * pyy + rxi[1] * pyx) + (rxr[2] * p2y + rxi[2] * p2x);
    Wb[(size_t)fy * 4096] = bf16_rne(Wre) | (bf16_rne(Wim) << 16);
    float nx = pyx * stx - pyy * sty;
    pyy = pyx * sty + pyy * stx;
    pyx = nx;
  }
}

// ---------------- K12: fused forward DFT (radix-4 folded both axes) ----------------
// Phase A (v1): y-DFT with radix-4 fold over y; thread owns x in {xg,+32,+64,+96}, 4 freqs.
// Cls: float2 plane[r][x][slot], slot = t ^ x ^ r (XOR-swizzled, 32 KB exact).
__global__ __launch_bounds__(256) void k12_fwd(const float* __restrict__ x,
                                               float* __restrict__ X2) {
  __shared__ __align__(16) float Cls[8192];
  const int bi = blockIdx.x;
  const int tid = threadIdx.x;
  const float* img = x + (size_t)bi * 16384;

  // Phase A: y-DFT, radix-4 fold over y.
  {
    const int tg = tid >> 5;  // 0..7
    const int xg = tid & 31;
    const int t_[4] = {4 * tg, 4 * tg + 2, 2 * tg + 1, 2 * tg + 17};  // t=31 computed, discarded
    const float sgn = (tg & 1) ? 1.f : -1.f;  // (-i)^t for odd t: -i (t%4==1) / +i (t%4==3)
    float pc[4], ps[4], stc[4], sts[4];
#pragma unroll
    for (int f = 0; f < 4; ++f) {
      __sincosf((float)t_[f] * PI2_128, &sts[f], &stc[f]);
      pc[f] = 1.f;
      ps[f] = 0.f;
    }
    float ar_[4][4] = {{0.f}}, ai_[4][4] = {{0.f}};  // [freq][m]
    for (int y = 0; y < 32; ++y) {
      float v[4][4];
#pragma unroll
      for (int k = 0; k < 4; ++k)
#pragma unroll
        for (int m = 0; m < 4; ++m) v[k][m] = img[(y + 32 * k) * 128 + xg + 32 * m];
#pragma unroll
      for (int m = 0; m < 4; ++m) {
        float s = v[0][m] + v[2][m], d = v[0][m] - v[2][m];
        float s2 = v[1][m] + v[3][m], d2 = (v[1][m] - v[3][m]) * sgn;
        float a0 = s + s2, a1 = s - s2;
        ar_[0][m] += a0 * pc[0];
        ai_[0][m] -= a0 * ps[0];
        ar_[1][m] += a1 * pc[1];
        ai_[1][m] -= a1 * ps[1];
        ar_[2][m] += d * pc[2] + d2 * ps[2];
        ai_[2][m] += -d * ps[2] + d2 * pc[2];
        ar_[3][m] += d * pc[3] + d2 * ps[3];
        ai_[3][m] += -d * ps[3] + d2 * pc[3];
      }
#pragma unroll
      for (int f = 0; f < 4; ++f) {
        float c = pc[f], s = ps[f];
        pc[f] = c * stc[f] - s * sts[f];
        ps[f] = s * stc[f] + c * sts[f];
      }
    }
    // In-register x-butterfly; write 4 planes at swizzled slots.
    float2* Cf2 = (float2*)Cls;
#pragma unroll
    for (int f = 0; f < 4; ++f) {
      int t = t_[f];
      float Ar = ar_[f][0] + ar_[f][2], Ai = ai_[f][0] + ai_[f][2];
      float Br = ar_[f][0] - ar_[f][2], Bi = ai_[f][0] - ai_[f][2];
      float Cr = ar_[f][1] + ar_[f][3], Ci = ai_[f][1] + ai_[f][3];
      float Dr = ar_[f][1] - ar_[f][3], Di = ai_[f][1] - ai_[f][3];
      const int rowb = xg * 32;
      const int sx = t ^ xg;
      Cf2[0 * 1024 + rowb + (sx ^ 0)] = make_float2(Ar + Cr, Ai + Ci);  // r=0: A+C
      Cf2[1 * 1024 + rowb + (sx ^ 1)] = make_float2(Br + Di, Bi - Dr);  // r=1: B-iD
      Cf2[2 * 1024 + rowb + (sx ^ 2)] = make_float2(Ar - Cr, Ai - Ci);  // r=2: A-C
      Cf2[3 * 1024 + rowb + (sx ^ 3)] = make_float2(Br - Di, Bi + Dr);  // r=3: B+iD
    }
  }
  __syncthreads();

  // Phase B: x-DFT on folded planes (32 samples per freq) + disk mask.
  {
    const int tg2 = tid >> 5;  // t-quad: t = 4*tg2 + tt
    const int fxg = tid & 31;
    float accr[2][4] = {{0.f}}, acci[2][4] = {{0.f}};
    int fxp_[2], r_[2];
    float pc2[2], ps2[2], stc2[2], sts2[2];
#pragma unroll
    for (int u = 0; u < 2; ++u) {
      fxp_[u] = k_flist[2 * fxg + u];
      r_[u] = (fxp_[u] + 2) & 3;
      float fx = (float)(fxp_[u] - 30);
      __sincosf(fx * PI2_128, &sts2[u], &stc2[u]);
      pc2[u] = 1.f;
      ps2[u] = 0.f;
    }
    const float2* Cf2 = (const float2*)Cls;
    const int ts = 4 * tg2;
    for (int xx = 0; xx < 32; ++xx) {
#pragma unroll
      for (int u = 0; u < 2; ++u) {
        const int base = r_[u] * 1024 + xx * 32;
        const int s0 = ts ^ xx ^ r_[u];  // (ts+j)^xx^r == s0^j (ts low2 = 0)
        float2 p0 = Cf2[base + s0];
        float2 p1 = Cf2[base + (s0 ^ 1)];
        float2 p2 = Cf2[base + (s0 ^ 2)];
        float2 p3 = Cf2[base + (s0 ^ 3)];
        float zr[4] = {p0.x, p1.x, p2.x, p3.x};
        float zi[4] = {p0.y, p1.y, p2.y, p3.y};
        float c = pc2[u], s = ps2[u];
#pragma unroll
        for (int tt = 0; tt < 4; ++tt) {
          accr[u][tt] += zr[tt] * c + zi[tt] * s;
          acci[u][tt] += zi[tt] * c - zr[tt] * s;
        }
        pc2[u] = c * stc2[u] - s * sts2[u];
        ps2[u] = s * stc2[u] + c * sts2[u];
      }
    }
    float2* X2c = (float2*)X2 + (size_t)bi * NF;
#pragma unroll
    for (int u = 0; u < 2; ++u) {
      if (2 * fxg + u >= 61) continue;
      int fxp = fxp_[u], fx = fxp - 30;
#pragma unroll
      for (int tt = 0; tt < 4; ++tt) {
        int t = 4 * tg2 + tt;
        if (t >= 31) continue;
        bool keep = (t * t + fx * fx) <= 900;
        X2c[fxp * 31 + t] =
            keep ? make_float2(accr[u][tt], acci[u][tt]) : make_float2(0.f, 0.f);
      }
    }
  }
}

// ---------------- KTX: X2[bi][f2] -> X2T[f2][i*16+b]  (64x64 float2 LDS tiles) ------
__global__ __launch_bounds__(256) void ktx(const float2* __restrict__ X2,
                                           float2* __restrict__ X2T) {
  __shared__ __align__(16) float2 Ld[4096];
  const int tid = threadIdx.x;
  const int tf = blockIdx.x % 30;  // f2 tile
  const int tc = blockIdx.x / 30;  // out-col tile: i0 = tc*4
  const int f2_0 = tf * 64;
  const int lo = tid & 63, hi = tid >> 6;
#pragma unroll
  for (int k = 0; k < 16; ++k) {
    int c = k * 4 + hi;  // local out-col: c = (i-i0)*16 + b
    int bi = (c & 15) * 64 + tc * 4 + (c >> 4);
    int f2 = f2_0 + lo;
    float2 v = (f2 < NF) ? X2[(size_t)bi * NF + f2] : make_float2(0.f, 0.f);
    Ld[(c << 6) | (lo ^ c)] = v;  // XOR-swizzled: conflict-free both phases
  }
  __syncthreads();
#pragma unroll
  for (int k = 0; k < 16; ++k) {
    int fr = k * 4 + hi;
    int f2 = f2_0 + fr;
    if (f2 < NF) X2T[(size_t)f2 * 1024 + tc * 64 + lo] = Ld[(lo << 6) | (fr ^ lo)];
  }
}

// ---------------- K3: per-frequency channel mix via MFMA (bf16, X split hi/lo) ----
__global__ __launch_bounds__(256) void k3_mfma(const float* X2T,
                                               const unsigned* __restrict__ WtB,
                                               float* F) {
  // bijective XCD-chunked blockIdx swizzle (m204 form)
  const int nwg = (int)gridDim.x;
  const int orig = (int)blockIdx.x;
  const int xcd = orig & 7;
  const int q = nwg >> 3, r = nwg & 7;
  const int blk = (xcd < r ? xcd * (q + 1) : r * (q + 1) + (xcd - r) * q) + (orig >> 3);

  const int tid = (int)threadIdx.x;
  const int wv = tid >> 6;
  const int g = blk * 4 + wv;
  const int f2v = g >> 1;
  const bool valid = f2v < NF;
  const int f2 = valid ? f2v : NF - 1;  // clamp keeps reads in the block's own rows
  const int half = g & 1;
  const int lane = tid & 63;
  const int m = lane & 15;   // A-row (output batch) == B-col-within-tile
  const int lg = lane >> 4;  // k lane-group
  const int bs = (m + 8) & 15;
  const int co = m & 1;      // re/im column parity

  // ---- A: gather X2T row f2 (coalesced); i = ks*16 + lg*4 + t ----
  float2 xv[4][4];
  const float2* Xc = (const float2*)X2T;
#pragma unroll
  for (int ks = 0; ks < 4; ++ks)
#pragma unroll
    for (int t = 0; t < 4; ++t)
      xv[ks][t] = Xc[(size_t)f2 * 1024 + (ks * 16 + lg * 4 + t) * 16 + bs];

  __syncthreads();  // all waves done reading their rows before any in-place store

  unsigned ahi[4][4], alo[4][4];
#pragma unroll
  for (int ks = 0; ks < 4; ++ks) {
#pragma unroll
    for (int t = 0; t < 4; ++t) {
      float xr = xv[ks][t].x, xi = xv[ks][t].y;
      unsigned hr = bf16_rne(xr), hi2 = bf16_rne(xi);
      float lr = xr - __uint_as_float(hr << 16);
      float li = xi - __uint_as_float(hi2 << 16);
      ahi[ks][t] = hr | (hi2 << 16);
      alo[ks][t] = bf16_rne(lr) | (bf16_rne(li) << 16);
    }
  }

  f32x4 acc[4];
#pragma unroll
  for (int nt = 0; nt < 4; ++nt) acc[nt] = {0.f, 0.f, 0.f, 0.f};

  const unsigned* Wb =
      WtB + (size_t)f2 * 4096 + half * 2048 + (lg * 8 + (m >> 1)) * 4;
#pragma unroll
  for (int ks = 0; ks < 4; ++ks) {
    bf16x8 bfr[4];
#pragma unroll
    for (int nt = 0; nt < 4; ++nt) {
      uint4 wq = *(const uint4*)(Wb + nt * 512 + ks * 128);
      unsigned b0, b1, b2, b3;
      if (co) {  // odd col: (Wi, Wr) = rot16(w)
        b0 = (wq.x >> 16) | (wq.x << 16);
        b1 = (wq.y >> 16) | (wq.y << 16);
        b2 = (wq.z >> 16) | (wq.z << 16);
        b3 = (wq.w >> 16) | (wq.w << 16);
      } else {   // even col: (Wr, -Wi) = w ^ signbit(hi)
        b0 = wq.x ^ 0x80000000u;
        b1 = wq.y ^ 0x80000000u;
        b2 = wq.z ^ 0x80000000u;
        b3 = wq.w ^ 0x80000000u;
      }
      bfr[nt] = mk_bf16x8(b0, b1, b2, b3);
    }
    bf16x8 ah = mk_bf16x8(ahi[ks][0], ahi[ks][1], ahi[ks][2], ahi[ks][3]);
    bf16x8 al = mk_bf16x8(alo[ks][0], alo[ks][1], alo[ks][2], alo[ks][3]);
#pragma unroll
    for (int nt = 0; nt < 4; ++nt)
      acc[nt] = __builtin_amdgcn_mfma_f32_16x16x32_bf16(ah, bfr[nt], acc[nt], 0, 0, 0);
#pragma unroll
    for (int nt = 0; nt < 4; ++nt)
      acc[nt] = __builtin_amdgcn_mfma_f32_16x16x32_bf16(al, bfr[nt], acc[nt], 0, 0, 0);
  }

  if (valid) {
    float* Fo = F + (size_t)f2 * 2048 + half * 64 + m;
#pragma unroll
    for (int nt = 0; nt < 4; ++nt)
#pragma unroll
      for (int rr = 0; rr < 4; ++rr)
        Fo[(lg * 4 + rr) * 128 + nt * 16] = acc[nt][rr];
  }
}

// ---------------- KTF: F[f2][bo] -> FT[bo][f2]  (64x64 float2 LDS tiles) -----------
__global__ __launch_bounds__(256) void ktf(const float2* __restrict__ F2,
                                           float2* __restrict__ FT) {
  __shared__ __align__(16) float2 Ld[4096];
  const int tid = threadIdx.x;
  const int tf = blockIdx.x % 30;
  const int tc = blockIdx.x / 30;
  const int f2_0 = tf * 64, c0 = tc * 64;
  const int lo = tid & 63, hi = tid >> 6;
#pragma unroll
  for (int k = 0; k < 16; ++k) {
    int fr = k * 4 + hi;
    int f2 = f2_0 + fr;
    float2 v = (f2 < NF) ? F2[(size_t)f2 * 1024 + c0 + lo] : make_float2(0.f, 0.f);
    Ld[(fr << 6) | (lo ^ fr)] = v;
  }
  __syncthreads();
#pragma unroll
  for (int k = 0; k < 16; ++k) {
    int cc = k * 4 + hi;
    int f2 = f2_0 + lo;
    if (f2 < NF) FT[(size_t)(c0 + cc) * NF + f2] = Ld[(lo << 6) | (cc ^ lo)];
  }
}

// ---------------- K45: inverse (radix-4 fold in x, parity fold in y) + bias ----------------
__global__ __launch_bounds__(256) void k45_out(const float* __restrict__ FT,
                                               const float* __restrict__ bias,
                                               float* __restrict__ out) {
  __shared__ __align__(16) float2 tw[128];  // e^{+2pi i m/128}
  __shared__ __align__(16) float U[61 * 132];
  __shared__ __align__(16) float TF[3904];  // union: Fl (phase<=1), then T
  const int b = blockIdx.x >> 6;
  const int o = blockIdx.x & 63;
  const int tid = threadIdx.x;
  float2* Fl = (float2*)TF;
  // FT layout [bo][NF] -> contiguous row load.
  const float2* Fc = (const float2*)FT + (size_t)(b * 64 + o) * NF;
  if (tid < 128) {
    float sv, cv;
    __sincosf((float)tid * PI2_128, &sv, &cv);
    tw[tid] = make_float2(cv, sv);
  }
  for (int j = tid; j < NF; j += 256) Fl[j] = Fc[j];
  __syncthreads();

  // Phase 1: inverse-x with output fold H(x+32k) = sum_r i^{rk} S_r
  {
    const int fy = tid & 31;
    const int xg = tid >> 3 >> 2;  // tid>>5: 0..7
    if (fy < 31) {
      float Sr[4][4] = {{0.f}}, Si[4][4] = {{0.f}};  // [r][j]
      float pr[4], pi[4], cr[4], ci[4];
#pragma unroll
      for (int j = 0; j < 4; ++j) {
        int xj = 4 * xg + j;
        float2 st = tw[xj];
        cr[j] = st.x;
        ci[j] = st.y;
        float2 p0 = tw[(-30 * xj) & 127];
        pr[j] = p0.x;
        pi[j] = p0.y;
      }
      const float2* Frow = Fl + fy;
      for (int f4 = 0; f4 < 60; f4 += 4) {
#pragma unroll
        for (int ss = 0; ss < 4; ++ss) {
          const int r = (ss + 2) & 3;  // fxp class pattern 2,3,0,1
          float2 fv = Frow[(f4 + ss) * 31];
#pragma unroll
          for (int j = 0; j < 4; ++j) {
            Sr[r][j] += fv.x * pr[j] - fv.y * pi[j];
            Si[r][j] += fv.x * pi[j] + fv.y * pr[j];
            float np = pr[j] * cr[j] - pi[j] * ci[j];
            pi[j] = pi[j] * cr[j] + pr[j] * ci[j];
            pr[j] = np;
          }
        }
      }
      {  // fxp = 60, class 2
        float2 fv = Frow[60 * 31];
#pragma unroll
        for (int j = 0; j < 4; ++j) {
          Sr[2][j] += fv.x * pr[j] - fv.y * pi[j];
          Si[2][j] += fv.x * pi[j] + fv.y * pr[j];
        }
      }
#pragma unroll
      for (int j = 0; j < 4; ++j) {
        int xj = 4 * xg + j;
        float Er = Sr[0][j] + Sr[2][j], Ei = Si[0][j] + Si[2][j];
        float Fr = Sr[0][j] - Sr[2][j], Fi = Si[0][j] - Si[2][j];
        float Gr = Sr[1][j] + Sr[3][j], Gi = Si[1][j] + Si[3][j];
        float Hr = Sr[1][j] - Sr[3][j], Hi = Si[1][j] - Si[3][j];
        U[fy * 132 + xj] = Er + Gr;
        U[fy * 132 + xj + 32] = Fr - Hi;   // F4 + iH
        U[fy * 132 + xj + 64] = Er - Gr;
        U[fy * 132 + xj + 96] = Fr + Hi;   // F4 - iH
        if (fy >= 1) {
          U[(30 + fy) * 132 + xj] = Ei + Gi;
          U[(30 + fy) * 132 + xj + 32] = Fi + Hr;
          U[(30 + fy) * 132 + xj + 64] = Ei - Gi;
          U[(30 + fy) * 132 + xj + 96] = Fi - Hr;
        }
      }
    }
  }
  __syncthreads();
  // Build T[c][y] (y<64) over Fl's dead storage.
  {
    const float sc1 = 1.f / 16384.f;
    float* T = TF;
    for (int j = tid; j < 61 * 64; j += 256) {
      int c = j >> 6, y = j & 63;
      float val;
      if (c == 0) val = sc1;
      else if (c <= 30) val = 2.f * sc1 * tw[(c * y) & 127].x;
      else val = -2.f * sc1 * tw[((c - 30) * y) & 127].y;
      T[j] = val;
    }
  }
  __syncthreads();
  // Phase 2: inverse-y with parity fold (even c -> P, odd c -> Q); out[y]=P+Q, out[y+64]=P-Q
  {
    const float* T = TF;
    const int yg = tid >> 5;
    const int xg = tid & 31;
    const int y0 = yg * 8, x0 = xg * 4;
    float Pa[8][4] = {{0.f}}, Qa[8][4] = {{0.f}};
    for (int c = 0; c < 60; c += 2) {
      float tf0[8], tf1[8], uf0[4], uf1[4];
      *(float4*)&tf0[0] = *(const float4*)(&T[c * 64 + y0]);
      *(float4*)&tf0[4] = *(const float4*)(&T[c * 64 + y0 + 4]);
      *(float4*)&tf1[0] = *(const float4*)(&T[(c + 1) * 64 + y0]);
      *(float4*)&tf1[4] = *(const float4*)(&T[(c + 1) * 64 + y0 + 4]);
      *(float4*)&uf0[0] = *(const float4*)(&U[c * 132 + x0]);
      *(float4*)&uf1[0] = *(const float4*)(&U[(c + 1) * 132 + x0]);
#pragma unroll
      for (int jy = 0; jy < 8; ++jy)
#pragma unroll
        for (int jx = 0; jx < 4; ++jx) {
          Pa[jy][jx] += tf0[jy] * uf0[jx];
          Qa[jy][jx] += tf1[jy] * uf1[jx];
        }
    }
    {  // c = 60 (even -> P)
      float tf0[8], uf0[4];
      *(float4*)&tf0[0] = *(const float4*)(&T[60 * 64 + y0]);
      *(float4*)&tf0[4] = *(const float4*)(&T[60 * 64 + y0 + 4]);
      *(float4*)&uf0[0] = *(const float4*)(&U[60 * 132 + x0]);
#pragma unroll
      for (int jy = 0; jy < 8; ++jy)
#pragma unroll
        for (int jx = 0; jx < 4; ++jx) Pa[jy][jx] += tf0[jy] * uf0[jx];
    }
    const float bo_ = bias[o];
    float* op = out + (size_t)(b * 64 + o) * 16384;
#pragma unroll
    for (int jy = 0; jy < 8; ++jy) {
      float4 lo, hi;
      lo.x = Pa[jy][0] + Qa[jy][0] + bo_;
      lo.y = Pa[jy][1] + Qa[jy][1] + bo_;
      lo.z = Pa[jy][2] + Qa[jy][2] + bo_;
      lo.w = Pa[jy][3] + Qa[jy][3] + bo_;
      hi.x = Pa[jy][0] - Qa[jy][0] + bo_;
      hi.y = Pa[jy][1] - Qa[jy][1] + bo_;
      hi.z = Pa[jy][2] - Qa[jy][2] + bo_;
      hi.w = Pa[jy][3] - Qa[jy][3] + bo_;
      *(float4*)(op + (y0 + jy) * 128 + x0) = lo;
      *(float4*)(op + (y0 + jy + 64) * 128 + x0) = hi;
    }
  }
}

extern "C" void kernel_launch(void* const* d_in, const int* in_sizes, int n_in,
                              void* d_out, int out_size, void* d_ws, size_t ws_size,
                              hipStream_t stream) {
  (void)in_sizes; (void)n_in; (void)out_size; (void)ws_size;
  const float* x = (const float*)d_in[0];
  const float* w = (const float*)d_in[1];
  const float* bias = (const float*)d_in[2];
  float* out = (float*)d_out;

  unsigned* Wt = (unsigned*)d_ws;
  float* A = (float*)d_ws + 7745536;    // X2, later FT
  float* B = (float*)d_ws + 11618304;   // X2T, in-place F

  k0_what<<<976, 256, 0, stream>>>(w, Wt);
  k12_fwd<<<1024, 256, 0, stream>>>(x, A);
  ktx<<<480, 256, 0, stream>>>((const float2*)A, (float2*)B);
  k3_mfma<<<946, 256, 0, stream>>>(B, Wt, B);
  ktf<<<480, 256, 0, stream>>>((const float2*)B, (float2*)A);
  k45_out<<<1024, 256, 0, stream>>>(A, bias, out);
}

// Round 10
// 224.131 us; speedup vs baseline: 1.5294x; 1.0053x over previous
//
#include <hip/hip_runtime.h>

// FFTConvNet: out[b,o] = IFFT2( M · sum_i X^[(b+8)%16, i] · W^[(o+32)%64, i] ) + bias[o]
// fftshift(no axes) shifts ALL dims -> batch roll 8, Cout roll 32; Cin rolls cancel.
// Disk mask fy^2+fx^2<=900. Half-spectrum: fy(t) in [0,30] (31), fx in [-30,30] (61), f2 = fxp*31+t.
// Pipeline: k012 (FUSED: blocks 0..1023 = fwd DFT -> X2 ; blocks 1024..1999 = W^ bf16 frag-order
//   -- independent work, one dispatch, overlapped; fills the 5th 32KB-LDS slot/CU) ;
//   ktx (X2 -> X2T[f2][i*16+b]) ; k3 (MFMA mix, in-place F) ; ktf (F -> FT[bo][f2]) ;
//   k45 (inverse, contiguous FT rows).
// k12 part: Cls = 4 planes x 1024 float2 = 32 KB exact, XOR swizzle slot = t ^ x ^ r.
//   (R8 post-mortem: t-half grid split regressed 3x — VGPR 148, 2x image fetch. ~67us floor alone.)
// ws (62 MB): WtB u32 [0, 7745536) ; A = X2 / FT float [7745536, +3872768) ;
//             B = X2T / F float [11618304, +3872768).

#define PI2_128 0.04908738521234052f  // 2*pi/128
#define NF 1891

typedef __attribute__((ext_vector_type(8))) short bf16x8;
typedef __attribute__((ext_vector_type(4))) float f32x4;

// fxp list ordered by class r=(fxp+2)&3 (= fx mod 4): c0(15), c1(15), c2(16), c3(15), 3 dummies.
__device__ const int k_flist[64] = {
    2, 6, 10, 14, 18, 22, 26, 30, 34, 38, 42, 46, 50, 54, 58,
    3, 7, 11, 15, 19, 23, 27, 31, 35, 39, 43, 47, 51, 55, 59,
    0, 4, 8, 12, 16, 20, 24, 28, 32, 36, 40, 44, 48, 52, 56, 60,
    1, 5, 9, 13, 17, 21, 25, 29, 33, 37, 41, 45, 49, 53, 57,
    0, 0, 0};

__device__ inline unsigned bf16_rne(float v) {
  unsigned u = __float_as_uint(v);
  return (u + 0x7FFFu + ((u >> 16) & 1u)) >> 16;
}

__device__ inline bf16x8 mk_bf16x8(unsigned a, unsigned b, unsigned c, unsigned d) {
  union { unsigned u[4]; bf16x8 v; } x;
  x.u[0] = a; x.u[1] = b; x.u[2] = c; x.u[3] = d;
  return x.v;
}

// ---------------- K012: fused forward DFT (blocks 0..1023) + W^ precompute (1024..1999) ----
__global__ __launch_bounds__(256) void k012(const float* __restrict__ x,
                                            float* __restrict__ X2,
                                            const float* __restrict__ w,
                                            unsigned* __restrict__ Wt) {
  __shared__ __align__(16) float Cls[8192];
  const int tid = threadIdx.x;

  if (blockIdx.x < 1024) {
    // ================= k12: fwd DFT for image bi =================
    const int bi = blockIdx.x;
    const float* img = x + (size_t)bi * 16384;

    // Phase A: y-DFT, radix-4 fold over y.
    {
      const int tg = tid >> 5;  // 0..7
      const int xg = tid & 31;
      const int t_[4] = {4 * tg, 4 * tg + 2, 2 * tg + 1, 2 * tg + 17};  // t=31 discarded
      const float sgn = (tg & 1) ? 1.f : -1.f;  // (-i)^t for odd t
      float pc[4], ps[4], stc[4], sts[4];
#pragma unroll
      for (int f = 0; f < 4; ++f) {
        __sincosf((float)t_[f] * PI2_128, &sts[f], &stc[f]);
        pc[f] = 1.f;
        ps[f] = 0.f;
      }
      float ar_[4][4] = {{0.f}}, ai_[4][4] = {{0.f}};  // [freq][m]
      for (int y = 0; y < 32; ++y) {
        float v[4][4];
#pragma unroll
        for (int k = 0; k < 4; ++k)
#pragma unroll
          for (int m = 0; m < 4; ++m) v[k][m] = img[(y + 32 * k) * 128 + xg + 32 * m];
#pragma unroll
        for (int m = 0; m < 4; ++m) {
          float s = v[0][m] + v[2][m], d = v[0][m] - v[2][m];
          float s2 = v[1][m] + v[3][m], d2 = (v[1][m] - v[3][m]) * sgn;
          float a0 = s + s2, a1 = s - s2;
          ar_[0][m] += a0 * pc[0];
          ai_[0][m] -= a0 * ps[0];
          ar_[1][m] += a1 * pc[1];
          ai_[1][m] -= a1 * ps[1];
          ar_[2][m] += d * pc[2] + d2 * ps[2];
          ai_[2][m] += -d * ps[2] + d2 * pc[2];
          ar_[3][m] += d * pc[3] + d2 * ps[3];
          ai_[3][m] += -d * ps[3] + d2 * pc[3];
        }
#pragma unroll
        for (int f = 0; f < 4; ++f) {
          float c = pc[f], s = ps[f];
          pc[f] = c * stc[f] - s * sts[f];
          ps[f] = s * stc[f] + c * sts[f];
        }
      }
      // In-register x-butterfly; write 4 planes at swizzled slots.
      float2* Cf2 = (float2*)Cls;
#pragma unroll
      for (int f = 0; f < 4; ++f) {
        int t = t_[f];
        float Ar = ar_[f][0] + ar_[f][2], Ai = ai_[f][0] + ai_[f][2];
        float Br = ar_[f][0] - ar_[f][2], Bi = ai_[f][0] - ai_[f][2];
        float Cr = ar_[f][1] + ar_[f][3], Ci = ai_[f][1] + ai_[f][3];
        float Dr = ar_[f][1] - ar_[f][3], Di = ai_[f][1] - ai_[f][3];
        const int rowb = xg * 32;
        const int sx = t ^ xg;
        Cf2[0 * 1024 + rowb + (sx ^ 0)] = make_float2(Ar + Cr, Ai + Ci);  // r=0: A+C
        Cf2[1 * 1024 + rowb + (sx ^ 1)] = make_float2(Br + Di, Bi - Dr);  // r=1: B-iD
        Cf2[2 * 1024 + rowb + (sx ^ 2)] = make_float2(Ar - Cr, Ai - Ci);  // r=2: A-C
        Cf2[3 * 1024 + rowb + (sx ^ 3)] = make_float2(Br - Di, Bi + Dr);  // r=3: B+iD
      }
    }
    __syncthreads();

    // Phase B: x-DFT on folded planes (32 samples per freq) + disk mask.
    {
      const int tg2 = tid >> 5;  // t-quad: t = 4*tg2 + tt
      const int fxg = tid & 31;
      float accr[2][4] = {{0.f}}, acci[2][4] = {{0.f}};
      int fxp_[2], r_[2];
      float pc2[2], ps2[2], stc2[2], sts2[2];
#pragma unroll
      for (int u = 0; u < 2; ++u) {
        fxp_[u] = k_flist[2 * fxg + u];
        r_[u] = (fxp_[u] + 2) & 3;
        float fx = (float)(fxp_[u] - 30);
        __sincosf(fx * PI2_128, &sts2[u], &stc2[u]);
        pc2[u] = 1.f;
        ps2[u] = 0.f;
      }
      const float2* Cf2 = (const float2*)Cls;
      const int ts = 4 * tg2;
      for (int xx = 0; xx < 32; ++xx) {
#pragma unroll
        for (int u = 0; u < 2; ++u) {
          const int base = r_[u] * 1024 + xx * 32;
          const int s0 = ts ^ xx ^ r_[u];  // (ts+j)^xx^r == s0^j (ts low2 = 0)
          float2 p0 = Cf2[base + s0];
          float2 p1 = Cf2[base + (s0 ^ 1)];
          float2 p2 = Cf2[base + (s0 ^ 2)];
          float2 p3 = Cf2[base + (s0 ^ 3)];
          float zr[4] = {p0.x, p1.x, p2.x, p3.x};
          float zi[4] = {p0.y, p1.y, p2.y, p3.y};
          float c = pc2[u], s = ps2[u];
#pragma unroll
          for (int tt = 0; tt < 4; ++tt) {
            accr[u][tt] += zr[tt] * c + zi[tt] * s;
            acci[u][tt] += zi[tt] * c - zr[tt] * s;
          }
          pc2[u] = c * stc2[u] - s * sts2[u];
          ps2[u] = s * stc2[u] + c * sts2[u];
        }
      }
      float2* X2c = (float2*)X2 + (size_t)bi * NF;
#pragma unroll
      for (int u = 0; u < 2; ++u) {
        if (2 * fxg + u >= 61) continue;
        int fxp = fxp_[u], fx = fxp - 30;
#pragma unroll
        for (int tt = 0; tt < 4; ++tt) {
          int t = 4 * tg2 + tt;
          if (t >= 31) continue;
          bool keep = (t * t + fx * fx) <= 900;
          X2c[fxp * 31 + t] =
              keep ? make_float2(accr[u][tt], acci[u][tt]) : make_float2(0.f, 0.f);
        }
      }
    }
  } else {
    // ================= k0: W^ precompute (bf16), separable 3x3 twiddles =================
    const int bid2 = (int)blockIdx.x - 1024;
    const int fxp = bid2 >> 4;  // 0..60
    const int ig = bid2 & 15;
    const int il = tid & 3;
    const int o = ((tid >> 5) << 3) | ((tid >> 2) & 7);
    const int i = ig * 4 + il;
    const int op = (o + 32) & 63;
    const float* wp = w + (size_t)(op * 64 + i) * 9;
    float w9[9];
#pragma unroll
    for (int k = 0; k < 9; ++k) w9[k] = wp[k];

    const float fx = (float)(fxp - 30);
    float sn, cs;
    __sincosf(fx * PI2_128, &sn, &cs);
    const float e1x = cs, e1y = -sn;
    const float e2x = e1x * e1x - e1y * e1y, e2y = 2.f * e1x * e1y;
    float rxr[3], rxi[3];
#pragma unroll
    for (int ky = 0; ky < 3; ++ky) {
      rxr[ky] = w9[ky * 3] + w9[ky * 3 + 1] * e1x + w9[ky * 3 + 2] * e2x;
      rxi[ky] = w9[ky * 3 + 1] * e1y + w9[ky * 3 + 2] * e2y;
    }
    float pyx = 1.f, pyy = 0.f;
    const float stx = 0.9987954562f, sty = -0.04906767433f;
    unsigned* Wb = Wt + (size_t)(fxp * 31) * 4096 + (o >> 3) * 512 + (i >> 4) * 128 +
                   (((i >> 2) & 3) * 8 + (o & 7)) * 4 + (i & 3);
    for (int fy = 0; fy < 31; ++fy) {
      float p2x = pyx * pyx - pyy * pyy, p2y = 2.f * pyx * pyy;
      float Wre = rxr[0] + (rxr[1] * pyx - rxi[1] * pyy) + (rxr[2] * p2x - rxi[2] * p2y);
      float Wim = rxi[0] + (rxr[1] * pyy + rxi[1] * pyx) + (rxr[2] * p2y + rxi[2] * p2x);
      Wb[(size_t)fy * 4096] = bf16_rne(Wre) | (bf16_rne(Wim) << 16);
      float nx = pyx * stx - pyy * sty;
      pyy = pyx * sty + pyy * stx;
      pyx = nx;
    }
  }
}

// ---------------- KTX: X2[bi][f2] -> X2T[f2][i*16+b]  (64x64 float2 LDS tiles) ------
__global__ __launch_bounds__(256) void ktx(const float2* __restrict__ X2,
                                           float2* __restrict__ X2T) {
  __shared__ __align__(16) float2 Ld[4096];
  const int tid = threadIdx.x;
  const int tf = blockIdx.x % 30;  // f2 tile
  const int tc = blockIdx.x / 30;  // out-col tile: i0 = tc*4
  const int f2_0 = tf * 64;
  const int lo = tid & 63, hi = tid >> 6;
#pragma unroll
  for (int k = 0; k < 16; ++k) {
    int c = k * 4 + hi;  // local out-col: c = (i-i0)*16 + b
    int bi = (c & 15) * 64 + tc * 4 + (c >> 4);
    int f2 = f2_0 + lo;
    float2 v = (f2 < NF) ? X2[(size_t)bi * NF + f2] : make_float2(0.f, 0.f);
    Ld[(c << 6) | (lo ^ c)] = v;  // XOR-swizzled: conflict-free both phases
  }
  __syncthreads();
#pragma unroll
  for (int k = 0; k < 16; ++k) {
    int fr = k * 4 + hi;
    int f2 = f2_0 + fr;
    if (f2 < NF) X2T[(size_t)f2 * 1024 + tc * 64 + lo] = Ld[(lo << 6) | (fr ^ lo)];
  }
}

// ---------------- K3: per-frequency channel mix via MFMA (bf16, X split hi/lo) ----
__global__ __launch_bounds__(256) void k3_mfma(const float* X2T,
                                               const unsigned* __restrict__ WtB,
                                               float* F) {
  // bijective XCD-chunked blockIdx swizzle (m204 form)
  const int nwg = (int)gridDim.x;
  const int orig = (int)blockIdx.x;
  const int xcd = orig & 7;
  const int q = nwg >> 3, r = nwg & 7;
  const int blk = (xcd < r ? xcd * (q + 1) : r * (q + 1) + (xcd - r) * q) + (orig >> 3);

  const int tid = (int)threadIdx.x;
  const int wv = tid >> 6;
  const int g = blk * 4 + wv;
  const int f2v = g >> 1;
  const bool valid = f2v < NF;
  const int f2 = valid ? f2v : NF - 1;  // clamp keeps reads in the block's own rows
  const int half = g & 1;
  const int lane = tid & 63;
  const int m = lane & 15;   // A-row (output batch) == B-col-within-tile
  const int lg = lane >> 4;  // k lane-group
  const int bs = (m + 8) & 15;
  const int co = m & 1;      // re/im column parity

  // ---- A: gather X2T row f2 (coalesced); i = ks*16 + lg*4 + t ----
  float2 xv[4][4];
  const float2* Xc = (const float2*)X2T;
#pragma unroll
  for (int ks = 0; ks < 4; ++ks)
#pragma unroll
    for (int t = 0; t < 4; ++t)
      xv[ks][t] = Xc[(size_t)f2 * 1024 + (ks * 16 + lg * 4 + t) * 16 + bs];

  __syncthreads();  // all waves done reading their rows before any in-place store

  unsigned ahi[4][4], alo[4][4];
#pragma unroll
  for (int ks = 0; ks < 4; ++ks) {
#pragma unroll
    for (int t = 0; t < 4; ++t) {
      float xr = xv[ks][t].x, xi = xv[ks][t].y;
      unsigned hr = bf16_rne(xr), hi2 = bf16_rne(xi);
      float lr = xr - __uint_as_float(hr << 16);
      float li = xi - __uint_as_float(hi2 << 16);
      ahi[ks][t] = hr | (hi2 << 16);
      alo[ks][t] = bf16_rne(lr) | (bf16_rne(li) << 16);
    }
  }

  f32x4 acc[4];
#pragma unroll
  for (int nt = 0; nt < 4; ++nt) acc[nt] = {0.f, 0.f, 0.f, 0.f};

  const unsigned* Wb =
      WtB + (size_t)f2 * 4096 + half * 2048 + (lg * 8 + (m >> 1)) * 4;
#pragma unroll
  for (int ks = 0; ks < 4; ++ks) {
    bf16x8 bfr[4];
#pragma unroll
    for (int nt = 0; nt < 4; ++nt) {
      uint4 wq = *(const uint4*)(Wb + nt * 512 + ks * 128);
      unsigned b0, b1, b2, b3;
      if (co) {  // odd col: (Wi, Wr) = rot16(w)
        b0 = (wq.x >> 16) | (wq.x << 16);
        b1 = (wq.y >> 16) | (wq.y << 16);
        b2 = (wq.z >> 16) | (wq.z << 16);
        b3 = (wq.w >> 16) | (wq.w << 16);
      } else {   // even col: (Wr, -Wi) = w ^ signbit(hi)
        b0 = wq.x ^ 0x80000000u;
        b1 = wq.y ^ 0x80000000u;
        b2 = wq.z ^ 0x80000000u;
        b3 = wq.w ^ 0x80000000u;
      }
      bfr[nt] = mk_bf16x8(b0, b1, b2, b3);
    }
    bf16x8 ah = mk_bf16x8(ahi[ks][0], ahi[ks][1], ahi[ks][2], ahi[ks][3]);
    bf16x8 al = mk_bf16x8(alo[ks][0], alo[ks][1], alo[ks][2], alo[ks][3]);
#pragma unroll
    for (int nt = 0; nt < 4; ++nt)
      acc[nt] = __builtin_amdgcn_mfma_f32_16x16x32_bf16(ah, bfr[nt], acc[nt], 0, 0, 0);
#pragma unroll
    for (int nt = 0; nt < 4; ++nt)
      acc[nt] = __builtin_amdgcn_mfma_f32_16x16x32_bf16(al, bfr[nt], acc[nt], 0, 0, 0);
  }

  if (valid) {
    float* Fo = F + (size_t)f2 * 2048 + half * 64 + m;
#pragma unroll
    for (int nt = 0; nt < 4; ++nt)
#pragma unroll
      for (int rr = 0; rr < 4; ++rr)
        Fo[(lg * 4 + rr) * 128 + nt * 16] = acc[nt][rr];
  }
}

// ---------------- KTF: F[f2][bo] -> FT[bo][f2]  (64x64 float2 LDS tiles) -----------
__global__ __launch_bounds__(256) void ktf(const float2* __restrict__ F2,
                                           float2* __restrict__ FT) {
  __shared__ __align__(16) float2 Ld[4096];
  const int tid = threadIdx.x;
  const int tf = blockIdx.x % 30;
  const int tc = blockIdx.x / 30;
  const int f2_0 = tf * 64, c0 = tc * 64;
  const int lo = tid & 63, hi = tid >> 6;
#pragma unroll
  for (int k = 0; k < 16; ++k) {
    int fr = k * 4 + hi;
    int f2 = f2_0 + fr;
    float2 v = (f2 < NF) ? F2[(size_t)f2 * 1024 + c0 + lo] : make_float2(0.f, 0.f);
    Ld[(fr << 6) | (lo ^ fr)] = v;
  }
  __syncthreads();
#pragma unroll
  for (int k = 0; k < 16; ++k) {
    int cc = k * 4 + hi;
    int f2 = f2_0 + lo;
    if (f2 < NF) FT[(size_t)(c0 + cc) * NF + f2] = Ld[(lo << 6) | (cc ^ lo)];
  }
}

// ---------------- K45: inverse (radix-4 fold in x, parity fold in y) + bias ----------------
__global__ __launch_bounds__(256) void k45_out(const float* __restrict__ FT,
                                               const float* __restrict__ bias,
                                               float* __restrict__ out) {
  __shared__ __align__(16) float2 tw[128];  // e^{+2pi i m/128}
  __shared__ __align__(16) float U[61 * 132];
  __shared__ __align__(16) float TF[3904];  // union: Fl (phase<=1), then T
  const int b = blockIdx.x >> 6;
  const int o = blockIdx.x & 63;
  const int tid = threadIdx.x;
  float2* Fl = (float2*)TF;
  // FT layout [bo][NF] -> contiguous row load.
  const float2* Fc = (const float2*)FT + (size_t)(b * 64 + o) * NF;
  if (tid < 128) {
    float sv, cv;
    __sincosf((float)tid * PI2_128, &sv, &cv);
    tw[tid] = make_float2(cv, sv);
  }
  for (int j = tid; j < NF; j += 256) Fl[j] = Fc[j];
  __syncthreads();

  // Phase 1: inverse-x with output fold H(x+32k) = sum_r i^{rk} S_r
  {
    const int fy = tid & 31;
    const int xg = tid >> 3 >> 2;  // tid>>5: 0..7
    if (fy < 31) {
      float Sr[4][4] = {{0.f}}, Si[4][4] = {{0.f}};  // [r][j]
      float pr[4], pi[4], cr[4], ci[4];
#pragma unroll
      for (int j = 0; j < 4; ++j) {
        int xj = 4 * xg + j;
        float2 st = tw[xj];
        cr[j] = st.x;
        ci[j] = st.y;
        float2 p0 = tw[(-30 * xj) & 127];
        pr[j] = p0.x;
        pi[j] = p0.y;
      }
      const float2* Frow = Fl + fy;
      for (int f4 = 0; f4 < 60; f4 += 4) {
#pragma unroll
        for (int ss = 0; ss < 4; ++ss) {
          const int r = (ss + 2) & 3;  // fxp class pattern 2,3,0,1
          float2 fv = Frow[(f4 + ss) * 31];
#pragma unroll
          for (int j = 0; j < 4; ++j) {
            Sr[r][j] += fv.x * pr[j] - fv.y * pi[j];
            Si[r][j] += fv.x * pi[j] + fv.y * pr[j];
            float np = pr[j] * cr[j] - pi[j] * ci[j];
            pi[j] = pi[j] * cr[j] + pr[j] * ci[j];
            pr[j] = np;
          }
        }
      }
      {  // fxp = 60, class 2
        float2 fv = Frow[60 * 31];
#pragma unroll
        for (int j = 0; j < 4; ++j) {
          Sr[2][j] += fv.x * pr[j] - fv.y * pi[j];
          Si[2][j] += fv.x * pi[j] + fv.y * pr[j];
        }
      }
#pragma unroll
      for (int j = 0; j < 4; ++j) {
        int xj = 4 * xg + j;
        float Er = Sr[0][j] + Sr[2][j], Ei = Si[0][j] + Si[2][j];
        float Fr = Sr[0][j] - Sr[2][j], Fi = Si[0][j] - Si[2][j];
        float Gr = Sr[1][j] + Sr[3][j], Gi = Si[1][j] + Si[3][j];
        float Hr = Sr[1][j] - Sr[3][j], Hi = Si[1][j] - Si[3][j];
        U[fy * 132 + xj] = Er + Gr;
        U[fy * 132 + xj + 32] = Fr - Hi;   // F4 + iH
        U[fy * 132 + xj + 64] = Er - Gr;
        U[fy * 132 + xj + 96] = Fr + Hi;   // F4 - iH
        if (fy >= 1) {
          U[(30 + fy) * 132 + xj] = Ei + Gi;
          U[(30 + fy) * 132 + xj + 32] = Fi + Hr;
          U[(30 + fy) * 132 + xj + 64] = Ei - Gi;
          U[(30 + fy) * 132 + xj + 96] = Fi - Hr;
        }
      }
    }
  }
  __syncthreads();
  // Build T[c][y] (y<64) over Fl's dead storage.
  {
    const float sc1 = 1.f / 16384.f;
    float* T = TF;
    for (int j = tid; j < 61 * 64; j += 256) {
      int c = j >> 6, y = j & 63;
      float val;
      if (c == 0) val = sc1;
      else if (c <= 30) val = 2.f * sc1 * tw[(c * y) & 127].x;
      else val = -2.f * sc1 * tw[((c - 30) * y) & 127].y;
      T[j] = val;
    }
  }
  __syncthreads();
  // Phase 2: inverse-y with parity fold (even c -> P, odd c -> Q); out[y]=P+Q, out[y+64]=P-Q
  {
    const float* T = TF;
    const int yg = tid >> 5;
    const int xg = tid & 31;
    const int y0 = yg * 8, x0 = xg * 4;
    float Pa[8][4] = {{0.f}}, Qa[8][4] = {{0.f}};
    for (int c = 0; c < 60; c += 2) {
      float tf0[8], tf1[8], uf0[4], uf1[4];
      *(float4*)&tf0[0] = *(const float4*)(&T[c * 64 + y0]);
      *(float4*)&tf0[4] = *(const float4*)(&T[c * 64 + y0 + 4]);
      *(float4*)&tf1[0] = *(const float4*)(&T[(c + 1) * 64 + y0]);
      *(float4*)&tf1[4] = *(const float4*)(&T[(c + 1) * 64 + y0 + 4]);
      *(float4*)&uf0[0] = *(const float4*)(&U[c * 132 + x0]);
      *(float4*)&uf1[0] = *(const float4*)(&U[(c + 1) * 132 + x0]);
#pragma unroll
      for (int jy = 0; jy < 8; ++jy)
#pragma unroll
        for (int jx = 0; jx < 4; ++jx) {
          Pa[jy][jx] += tf0[jy] * uf0[jx];
          Qa[jy][jx] += tf1[jy] * uf1[jx];
        }
    }
    {  // c = 60 (even -> P)
      float tf0[8], uf0[4];
      *(float4*)&tf0[0] = *(const float4*)(&T[60 * 64 + y0]);
      *(float4*)&tf0[4] = *(const float4*)(&T[60 * 64 + y0 + 4]);
      *(float4*)&uf0[0] = *(const float4*)(&U[60 * 132 + x0]);
#pragma unroll
      for (int jy = 0; jy < 8; ++jy)
#pragma unroll
        for (int jx = 0; jx < 4; ++jx) Pa[jy][jx] += tf0[jy] * uf0[jx];
    }
    const float bo_ = bias[o];
    float* op = out + (size_t)(b * 64 + o) * 16384;
#pragma unroll
    for (int jy = 0; jy < 8; ++jy) {
      float4 lo, hi;
      lo.x = Pa[jy][0] + Qa[jy][0] + bo_;
      lo.y = Pa[jy][1] + Qa[jy][1] + bo_;
      lo.z = Pa[jy][2] + Qa[jy][2] + bo_;
      lo.w = Pa[jy][3] + Qa[jy][3] + bo_;
      hi.x = Pa[jy][0] - Qa[jy][0] + bo_;
      hi.y = Pa[jy][1] - Qa[jy][1] + bo_;
      hi.z = Pa[jy][2] - Qa[jy][2] + bo_;
      hi.w = Pa[jy][3] - Qa[jy][3] + bo_;
      *(float4*)(op + (y0 + jy) * 128 + x0) = lo;
      *(float4*)(op + (y0 + jy + 64) * 128 + x0) = hi;
    }
  }
}

extern "C" void kernel_launch(void* const* d_in, const int* in_sizes, int n_in,
                              void* d_out, int out_size, void* d_ws, size_t ws_size,
                              hipStream_t stream) {
  (void)in_sizes; (void)n_in; (void)out_size; (void)ws_size;
  const float* x = (const float*)d_in[0];
  const float* w = (const float*)d_in[1];
  const float* bias = (const float*)d_in[2];
  float* out = (float*)d_out;

  unsigned* Wt = (unsigned*)d_ws;
  float* A = (float*)d_ws + 7745536;    // X2, later FT
  float* B = (float*)d_ws + 11618304;   // X2T, in-place F

  k012<<<2000, 256, 0, stream>>>(x, A, w, Wt);
  ktx<<<480, 256, 0, stream>>>((const float2*)A, (float2*)B);
  k3_mfma<<<946, 256, 0, stream>>>(B, Wt, B);
  ktf<<<480, 256, 0, stream>>>((const float2*)B, (float2*)A);
  k45_out<<<1024, 256, 0, stream>>>(A, bias, out);
}

// Round 11
// 219.769 us; speedup vs baseline: 1.5598x; 1.0198x over previous
//
#include <hip/hip_runtime.h>

// FFTConvNet: out[b,o] = IFFT2( M · sum_i X^[(b+8)%16, i] · W^[(o+32)%64, i] ) + bias[o]
// fftshift(no axes) shifts ALL dims -> batch roll 8, Cout roll 32; Cin rolls cancel.
// Disk mask fy^2+fx^2<=900. Half-spectrum: fy(t) in [0,30] (31), fx in [-30,30] (61), f2 = fxp*31+t.
// Pipeline: k012 (FUSED: blocks 0..1023 = fwd DFT -> X2 ; 1024..1999 = W^ bf16 frag-order) ;
//   ktx (X2 -> X2T[f2][i*16+b]) ; k3 (MFMA mix, in-place F) ; ktf (F -> FT[bo][f2]) ;
//   k45 (inverse: phase1 VALU inverse-x -> U ; phase2 = MFMA GEMM out = T^T x U, P/Q split,
//        T on-the-fly from tw, 3-term bf16 hi/lo split -- same fragment convention as k3).
// k12 part: Cls = 4 planes x 1024 float2 = 32 KB exact, XOR swizzle slot = t ^ x ^ r.
// ws (62 MB): WtB u32 [0, 7745536) ; A = X2 / FT float [7745536, +3872768) ;
//             B = X2T / F float [11618304, +3872768).

#define PI2_128 0.04908738521234052f  // 2*pi/128
#define NF 1891

typedef __attribute__((ext_vector_type(8))) short bf16x8;
typedef __attribute__((ext_vector_type(4))) float f32x4;

// fxp list ordered by class r=(fxp+2)&3 (= fx mod 4): c0(15), c1(15), c2(16), c3(15), 3 dummies.
__device__ const int k_flist[64] = {
    2, 6, 10, 14, 18, 22, 26, 30, 34, 38, 42, 46, 50, 54, 58,
    3, 7, 11, 15, 19, 23, 27, 31, 35, 39, 43, 47, 51, 55, 59,
    0, 4, 8, 12, 16, 20, 24, 28, 32, 36, 40, 44, 48, 52, 56, 60,
    1, 5, 9, 13, 17, 21, 25, 29, 33, 37, 41, 45, 49, 53, 57,
    0, 0, 0};

__device__ inline unsigned bf16_rne(float v) {
  unsigned u = __float_as_uint(v);
  return (u + 0x7FFFu + ((u >> 16) & 1u)) >> 16;
}

__device__ inline bf16x8 mk_bf16x8(unsigned a, unsigned b, unsigned c, unsigned d) {
  union { unsigned u[4]; bf16x8 v; } x;
  x.u[0] = a; x.u[1] = b; x.u[2] = c; x.u[3] = d;
  return x.v;
}

// ---------------- K012: fused forward DFT (blocks 0..1023) + W^ precompute (1024..1999) ----
__global__ __launch_bounds__(256) void k012(const float* __restrict__ x,
                                            float* __restrict__ X2,
                                            const float* __restrict__ w,
                                            unsigned* __restrict__ Wt) {
  __shared__ __align__(16) float Cls[8192];
  const int tid = threadIdx.x;

  if (blockIdx.x < 1024) {
    // ================= k12: fwd DFT for image bi =================
    const int bi = blockIdx.x;
    const float* img = x + (size_t)bi * 16384;

    // Phase A: y-DFT, radix-4 fold over y.
    {
      const int tg = tid >> 5;  // 0..7
      const int xg = tid & 31;
      const int t_[4] = {4 * tg, 4 * tg + 2, 2 * tg + 1, 2 * tg + 17};  // t=31 discarded
      const float sgn = (tg & 1) ? 1.f : -1.f;  // (-i)^t for odd t
      float pc[4], ps[4], stc[4], sts[4];
#pragma unroll
      for (int f = 0; f < 4; ++f) {
        __sincosf((float)t_[f] * PI2_128, &sts[f], &stc[f]);
        pc[f] = 1.f;
        ps[f] = 0.f;
      }
      float ar_[4][4] = {{0.f}}, ai_[4][4] = {{0.f}};  // [freq][m]
      for (int y = 0; y < 32; ++y) {
        float v[4][4];
#pragma unroll
        for (int k = 0; k < 4; ++k)
#pragma unroll
          for (int m = 0; m < 4; ++m) v[k][m] = img[(y + 32 * k) * 128 + xg + 32 * m];
#pragma unroll
        for (int m = 0; m < 4; ++m) {
          float s = v[0][m] + v[2][m], d = v[0][m] - v[2][m];
          float s2 = v[1][m] + v[3][m], d2 = (v[1][m] - v[3][m]) * sgn;
          float a0 = s + s2, a1 = s - s2;
          ar_[0][m] += a0 * pc[0];
          ai_[0][m] -= a0 * ps[0];
          ar_[1][m] += a1 * pc[1];
          ai_[1][m] -= a1 * ps[1];
          ar_[2][m] += d * pc[2] + d2 * ps[2];
          ai_[2][m] += -d * ps[2] + d2 * pc[2];
          ar_[3][m] += d * pc[3] + d2 * ps[3];
          ai_[3][m] += -d * ps[3] + d2 * pc[3];
        }
#pragma unroll
        for (int f = 0; f < 4; ++f) {
          float c = pc[f], s = ps[f];
          pc[f] = c * stc[f] - s * sts[f];
          ps[f] = s * stc[f] + c * sts[f];
        }
      }
      // In-register x-butterfly; write 4 planes at swizzled slots.
      float2* Cf2 = (float2*)Cls;
#pragma unroll
      for (int f = 0; f < 4; ++f) {
        int t = t_[f];
        float Ar = ar_[f][0] + ar_[f][2], Ai = ai_[f][0] + ai_[f][2];
        float Br = ar_[f][0] - ar_[f][2], Bi = ai_[f][0] - ai_[f][2];
        float Cr = ar_[f][1] + ar_[f][3], Ci = ai_[f][1] + ai_[f][3];
        float Dr = ar_[f][1] - ar_[f][3], Di = ai_[f][1] - ai_[f][3];
        const int rowb = xg * 32;
        const int sx = t ^ xg;
        Cf2[0 * 1024 + rowb + (sx ^ 0)] = make_float2(Ar + Cr, Ai + Ci);  // r=0: A+C
        Cf2[1 * 1024 + rowb + (sx ^ 1)] = make_float2(Br + Di, Bi - Dr);  // r=1: B-iD
        Cf2[2 * 1024 + rowb + (sx ^ 2)] = make_float2(Ar - Cr, Ai - Ci);  // r=2: A-C
        Cf2[3 * 1024 + rowb + (sx ^ 3)] = make_float2(Br - Di, Bi + Dr);  // r=3: B+iD
      }
    }
    __syncthreads();

    // Phase B: x-DFT on folded planes (32 samples per freq) + disk mask.
    {
      const int tg2 = tid >> 5;  // t-quad: t = 4*tg2 + tt
      const int fxg = tid & 31;
      float accr[2][4] = {{0.f}}, acci[2][4] = {{0.f}};
      int fxp_[2], r_[2];
      float pc2[2], ps2[2], stc2[2], sts2[2];
#pragma unroll
      for (int u = 0; u < 2; ++u) {
        fxp_[u] = k_flist[2 * fxg + u];
        r_[u] = (fxp_[u] + 2) & 3;
        float fx = (float)(fxp_[u] - 30);
        __sincosf(fx * PI2_128, &sts2[u], &stc2[u]);
        pc2[u] = 1.f;
        ps2[u] = 0.f;
      }
      const float2* Cf2 = (const float2*)Cls;
      const int ts = 4 * tg2;
      for (int xx = 0; xx < 32; ++xx) {
#pragma unroll
        for (int u = 0; u < 2; ++u) {
          const int base = r_[u] * 1024 + xx * 32;
          const int s0 = ts ^ xx ^ r_[u];  // (ts+j)^xx^r == s0^j (ts low2 = 0)
          float2 p0 = Cf2[base + s0];
          float2 p1 = Cf2[base + (s0 ^ 1)];
          float2 p2 = Cf2[base + (s0 ^ 2)];
          float2 p3 = Cf2[base + (s0 ^ 3)];
          float zr[4] = {p0.x, p1.x, p2.x, p3.x};
          float zi[4] = {p0.y, p1.y, p2.y, p3.y};
          float c = pc2[u], s = ps2[u];
#pragma unroll
          for (int tt = 0; tt < 4; ++tt) {
            accr[u][tt] += zr[tt] * c + zi[tt] * s;
            acci[u][tt] += zi[tt] * c - zr[tt] * s;
          }
          pc2[u] = c * stc2[u] - s * sts2[u];
          ps2[u] = s * stc2[u] + c * sts2[u];
        }
      }
      float2* X2c = (float2*)X2 + (size_t)bi * NF;
#pragma unroll
      for (int u = 0; u < 2; ++u) {
        if (2 * fxg + u >= 61) continue;
        int fxp = fxp_[u], fx = fxp - 30;
#pragma unroll
        for (int tt = 0; tt < 4; ++tt) {
          int t = 4 * tg2 + tt;
          if (t >= 31) continue;
          bool keep = (t * t + fx * fx) <= 900;
          X2c[fxp * 31 + t] =
              keep ? make_float2(accr[u][tt], acci[u][tt]) : make_float2(0.f, 0.f);
        }
      }
    }
  } else {
    // ================= k0: W^ precompute (bf16), separable 3x3 twiddles =================
    const int bid2 = (int)blockIdx.x - 1024;
    const int fxp = bid2 >> 4;  // 0..60
    const int ig = bid2 & 15;
    const int il = tid & 3;
    const int o = ((tid >> 5) << 3) | ((tid >> 2) & 7);
    const int i = ig * 4 + il;
    const int op = (o + 32) & 63;
    const float* wp = w + (size_t)(op * 64 + i) * 9;
    float w9[9];
#pragma unroll
    for (int k = 0; k < 9; ++k) w9[k] = wp[k];

    const float fx = (float)(fxp - 30);
    float sn, cs;
    __sincosf(fx * PI2_128, &sn, &cs);
    const float e1x = cs, e1y = -sn;
    const float e2x = e1x * e1x - e1y * e1y, e2y = 2.f * e1x * e1y;
    float rxr[3], rxi[3];
#pragma unroll
    for (int ky = 0; ky < 3; ++ky) {
      rxr[ky] = w9[ky * 3] + w9[ky * 3 + 1] * e1x + w9[ky * 3 + 2] * e2x;
      rxi[ky] = w9[ky * 3 + 1] * e1y + w9[ky * 3 + 2] * e2y;
    }
    float pyx = 1.f, pyy = 0.f;
    const float stx = 0.9987954562f, sty = -0.04906767433f;
    unsigned* Wb = Wt + (size_t)(fxp * 31) * 4096 + (o >> 3) * 512 + (i >> 4) * 128 +
                   (((i >> 2) & 3) * 8 + (o & 7)) * 4 + (i & 3);
    for (int fy = 0; fy < 31; ++fy) {
      float p2x = pyx * pyx - pyy * pyy, p2y = 2.f * pyx * pyy;
      float Wre = rxr[0] + (rxr[1] * pyx - rxi[1] * pyy) + (rxr[2] * p2x - rxi[2] * p2y);
      float Wim = rxi[0] + (rxr[1] * pyy + rxi[1] * pyx) + (rxr[2] * p2y + rxi[2] * p2x);
      Wb[(size_t)fy * 4096] = bf16_rne(Wre) | (bf16_rne(Wim) << 16);
      float nx = pyx * stx - pyy * sty;
      pyy = pyx * sty + pyy * stx;
      pyx = nx;
    }
  }
}

// ---------------- KTX: X2[bi][f2] -> X2T[f2][i*16+b]  (64x64 float2 LDS tiles) ------
__global__ __launch_bounds__(256) void ktx(const float2* __restrict__ X2,
                                           float2* __restrict__ X2T) {
  __shared__ __align__(16) float2 Ld[4096];
  const int tid = threadIdx.x;
  const int tf = blockIdx.x % 30;  // f2 tile
  const int tc = blockIdx.x / 30;  // out-col tile: i0 = tc*4
  const int f2_0 = tf * 64;
  const int lo = tid & 63, hi = tid >> 6;
#pragma unroll
  for (int k = 0; k < 16; ++k) {
    int c = k * 4 + hi;  // local out-col: c = (i-i0)*16 + b
    int bi = (c & 15) * 64 + tc * 4 + (c >> 4);
    int f2 = f2_0 + lo;
    float2 v = (f2 < NF) ? X2[(size_t)bi * NF + f2] : make_float2(0.f, 0.f);
    Ld[(c << 6) | (lo ^ c)] = v;  // XOR-swizzled: conflict-free both phases
  }
  __syncthreads();
#pragma unroll
  for (int k = 0; k < 16; ++k) {
    int fr = k * 4 + hi;
    int f2 = f2_0 + fr;
    if (f2 < NF) X2T[(size_t)f2 * 1024 + tc * 64 + lo] = Ld[(lo << 6) | (fr ^ lo)];
  }
}

// ---------------- K3: per-frequency channel mix via MFMA (bf16, X split hi/lo) ----
__global__ __launch_bounds__(256) void k3_mfma(const float* X2T,
                                               const unsigned* __restrict__ WtB,
                                               float* F) {
  // bijective XCD-chunked blockIdx swizzle (m204 form)
  const int nwg = (int)gridDim.x;
  const int orig = (int)blockIdx.x;
  const int xcd = orig & 7;
  const int q = nwg >> 3, r = nwg & 7;
  const int blk = (xcd < r ? xcd * (q + 1) : r * (q + 1) + (xcd - r) * q) + (orig >> 3);

  const int tid = (int)threadIdx.x;
  const int wv = tid >> 6;
  const int g = blk * 4 + wv;
  const int f2v = g >> 1;
  const bool valid = f2v < NF;
  const int f2 = valid ? f2v : NF - 1;  // clamp keeps reads in the block's own rows
  const int half = g & 1;
  const int lane = tid & 63;
  const int m = lane & 15;   // A-row (output batch) == B-col-within-tile
  const int lg = lane >> 4;  // k lane-group
  const int bs = (m + 8) & 15;
  const int co = m & 1;      // re/im column parity

  // ---- A: gather X2T row f2 (coalesced); i = ks*16 + lg*4 + t ----
  float2 xv[4][4];
  const float2* Xc = (const float2*)X2T;
#pragma unroll
  for (int ks = 0; ks < 4; ++ks)
#pragma unroll
    for (int t = 0; t < 4; ++t)
      xv[ks][t] = Xc[(size_t)f2 * 1024 + (ks * 16 + lg * 4 + t) * 16 + bs];

  __syncthreads();  // all waves done reading their rows before any in-place store

  unsigned ahi[4][4], alo[4][4];
#pragma unroll
  for (int ks = 0; ks < 4; ++ks) {
#pragma unroll
    for (int t = 0; t < 4; ++t) {
      float xr = xv[ks][t].x, xi = xv[ks][t].y;
      unsigned hr = bf16_rne(xr), hi2 = bf16_rne(xi);
      float lr = xr - __uint_as_float(hr << 16);
      float li = xi - __uint_as_float(hi2 << 16);
      ahi[ks][t] = hr | (hi2 << 16);
      alo[ks][t] = bf16_rne(lr) | (bf16_rne(li) << 16);
    }
  }

  f32x4 acc[4];
#pragma unroll
  for (int nt = 0; nt < 4; ++nt) acc[nt] = {0.f, 0.f, 0.f, 0.f};

  const unsigned* Wb =
      WtB + (size_t)f2 * 4096 + half * 2048 + (lg * 8 + (m >> 1)) * 4;
#pragma unroll
  for (int ks = 0; ks < 4; ++ks) {
    bf16x8 bfr[4];
#pragma unroll
    for (int nt = 0; nt < 4; ++nt) {
      uint4 wq = *(const uint4*)(Wb + nt * 512 + ks * 128);
      unsigned b0, b1, b2, b3;
      if (co) {  // odd col: (Wi, Wr) = rot16(w)
        b0 = (wq.x >> 16) | (wq.x << 16);
        b1 = (wq.y >> 16) | (wq.y << 16);
        b2 = (wq.z >> 16) | (wq.z << 16);
        b3 = (wq.w >> 16) | (wq.w << 16);
      } else {   // even col: (Wr, -Wi) = w ^ signbit(hi)
        b0 = wq.x ^ 0x80000000u;
        b1 = wq.y ^ 0x80000000u;
        b2 = wq.z ^ 0x80000000u;
        b3 = wq.w ^ 0x80000000u;
      }
      bfr[nt] = mk_bf16x8(b0, b1, b2, b3);
    }
    bf16x8 ah = mk_bf16x8(ahi[ks][0], ahi[ks][1], ahi[ks][2], ahi[ks][3]);
    bf16x8 al = mk_bf16x8(alo[ks][0], alo[ks][1], alo[ks][2], alo[ks][3]);
#pragma unroll
    for (int nt = 0; nt < 4; ++nt)
      acc[nt] = __builtin_amdgcn_mfma_f32_16x16x32_bf16(ah, bfr[nt], acc[nt], 0, 0, 0);
#pragma unroll
    for (int nt = 0; nt < 4; ++nt)
      acc[nt] = __builtin_amdgcn_mfma_f32_16x16x32_bf16(al, bfr[nt], acc[nt], 0, 0, 0);
  }

  if (valid) {
    float* Fo = F + (size_t)f2 * 2048 + half * 64 + m;
#pragma unroll
    for (int nt = 0; nt < 4; ++nt)
#pragma unroll
      for (int rr = 0; rr < 4; ++rr)
        Fo[(lg * 4 + rr) * 128 + nt * 16] = acc[nt][rr];
  }
}

// ---------------- KTF: F[f2][bo] -> FT[bo][f2]  (64x64 float2 LDS tiles) -----------
__global__ __launch_bounds__(256) void ktf(const float2* __restrict__ F2,
                                           float2* __restrict__ FT) {
  __shared__ __align__(16) float2 Ld[4096];
  const int tid = threadIdx.x;
  const int tf = blockIdx.x % 30;
  const int tc = blockIdx.x / 30;
  const int f2_0 = tf * 64, c0 = tc * 64;
  const int lo = tid & 63, hi = tid >> 6;
#pragma unroll
  for (int k = 0; k < 16; ++k) {
    int fr = k * 4 + hi;
    int f2 = f2_0 + fr;
    float2 v = (f2 < NF) ? F2[(size_t)f2 * 1024 + c0 + lo] : make_float2(0.f, 0.f);
    Ld[(fr << 6) | (lo ^ fr)] = v;
  }
  __syncthreads();
#pragma unroll
  for (int k = 0; k < 16; ++k) {
    int cc = k * 4 + hi;
    int f2 = f2_0 + lo;
    if (f2 < NF) FT[(size_t)(c0 + cc) * NF + f2] = Ld[(lo << 6) | (cc ^ lo)];
  }
}

// ---------------- K45: inverse (radix-4 fold in x) + MFMA inverse-y + bias ----------
__global__ __launch_bounds__(256) void k45_out(const float* __restrict__ FT,
                                               const float* __restrict__ bias,
                                               float* __restrict__ out) {
  __shared__ __align__(16) float2 tw[128];  // e^{+2pi i m/128}
  __shared__ __align__(16) float U[61 * 132];
  __shared__ __align__(16) float TF[3904];  // Fl staging (phase 1 only)
  const int b = blockIdx.x >> 6;
  const int o = blockIdx.x & 63;
  const int tid = threadIdx.x;
  float2* Fl = (float2*)TF;
  // FT layout [bo][NF] -> contiguous row load.
  const float2* Fc = (const float2*)FT + (size_t)(b * 64 + o) * NF;
  if (tid < 128) {
    float sv, cv;
    __sincosf((float)tid * PI2_128, &sv, &cv);
    tw[tid] = make_float2(cv, sv);
  }
  for (int j = tid; j < NF; j += 256) Fl[j] = Fc[j];
  __syncthreads();

  // Phase 1: inverse-x with output fold H(x+32k) = sum_r i^{rk} S_r
  {
    const int fy = tid & 31;
    const int xg = tid >> 3 >> 2;  // tid>>5: 0..7
    if (fy < 31) {
      float Sr[4][4] = {{0.f}}, Si[4][4] = {{0.f}};  // [r][j]
      float pr[4], pi[4], cr[4], ci[4];
#pragma unroll
      for (int j = 0; j < 4; ++j) {
        int xj = 4 * xg + j;
        float2 st = tw[xj];
        cr[j] = st.x;
        ci[j] = st.y;
        float2 p0 = tw[(-30 * xj) & 127];
        pr[j] = p0.x;
        pi[j] = p0.y;
      }
      const float2* Frow = Fl + fy;
      for (int f4 = 0; f4 < 60; f4 += 4) {
#pragma unroll
        for (int ss = 0; ss < 4; ++ss) {
          const int r = (ss + 2) & 3;  // fxp class pattern 2,3,0,1
          float2 fv = Frow[(f4 + ss) * 31];
#pragma unroll
          for (int j = 0; j < 4; ++j) {
            Sr[r][j] += fv.x * pr[j] - fv.y * pi[j];
            Si[r][j] += fv.x * pi[j] + fv.y * pr[j];
            float np = pr[j] * cr[j] - pi[j] * ci[j];
            pi[j] = pi[j] * cr[j] + pr[j] * ci[j];
            pr[j] = np;
          }
        }
      }
      {  // fxp = 60, class 2
        float2 fv = Frow[60 * 31];
#pragma unroll
        for (int j = 0; j < 4; ++j) {
          Sr[2][j] += fv.x * pr[j] - fv.y * pi[j];
          Si[2][j] += fv.x * pi[j] + fv.y * pr[j];
        }
      }
#pragma unroll
      for (int j = 0; j < 4; ++j) {
        int xj = 4 * xg + j;
        float Er = Sr[0][j] + Sr[2][j], Ei = Si[0][j] + Si[2][j];
        float Fr = Sr[0][j] - Sr[2][j], Fi = Si[0][j] - Si[2][j];
        float Gr = Sr[1][j] + Sr[3][j], Gi = Si[1][j] + Si[3][j];
        float Hr = Sr[1][j] - Sr[3][j], Hi = Si[1][j] - Si[3][j];
        U[fy * 132 + xj] = Er + Gr;
        U[fy * 132 + xj + 32] = Fr - Hi;   // F4 + iH
        U[fy * 132 + xj + 64] = Er - Gr;
        U[fy * 132 + xj + 96] = Fr + Hi;   // F4 - iH
        if (fy >= 1) {
          U[(30 + fy) * 132 + xj] = Ei + Gi;
          U[(30 + fy) * 132 + xj + 32] = Fi + Hr;
          U[(30 + fy) * 132 + xj + 64] = Ei - Gi;
          U[(30 + fy) * 132 + xj + 96] = Fi - Hr;
        }
      }
    }
  }
  __syncthreads();

  // Phase 2 (MFMA): out rows y (M=64) x cols x (N=128). P = even-c GEMM, Q = odd-c GEMM,
  // K=32 (one MFMA step). A = T on-the-fly from tw; B = U from LDS. 3-term bf16 hi/lo split.
  // Fragment convention identical to k3 (A lane&15 = M, B lane&15 = N, D row=(lane>>4)*4+reg).
  {
    const int wv = tid >> 6;       // wave -> y-tile
    const int lane = tid & 63;
    const int mm = lane & 15;
    const int kg = lane >> 4;      // k-group
    const int yA = wv * 16 + mm;   // A-frag row (y)
    const float sc1 = 1.f / 16384.f;

    unsigned aPh[4], aPl[4], aQh[4], aQl[4];
#pragma unroll
    for (int pr = 0; pr < 4; ++pr) {
      unsigned hP[2], lP[2], hQ[2], lQ[2];
#pragma unroll
      for (int h2 = 0; h2 < 2; ++h2) {
        int s = pr * 2 + h2;
        int ce = 16 * kg + 2 * s;  // even c for P
        int co = ce + 1;           // odd c for Q
        float vP, vQ;
        if (ce == 0) vP = sc1;
        else if (ce <= 30) vP = 2.f * sc1 * tw[(ce * yA) & 127].x;
        else if (ce <= 60) vP = -2.f * sc1 * tw[((ce - 30) * yA) & 127].y;
        else vP = 0.f;
        if (co <= 30) vQ = 2.f * sc1 * tw[(co * yA) & 127].x;
        else if (co <= 59) vQ = -2.f * sc1 * tw[((co - 30) * yA) & 127].y;
        else vQ = 0.f;
        unsigned h = bf16_rne(vP);
        hP[h2] = h;
        lP[h2] = bf16_rne(vP - __uint_as_float(h << 16));
        h = bf16_rne(vQ);
        hQ[h2] = h;
        lQ[h2] = bf16_rne(vQ - __uint_as_float(h << 16));
      }
      aPh[pr] = hP[0] | (hP[1] << 16);
      aPl[pr] = lP[0] | (lP[1] << 16);
      aQh[pr] = hQ[0] | (hQ[1] << 16);
      aQl[pr] = lQ[0] | (lQ[1] << 16);
    }
    const bf16x8 APh = mk_bf16x8(aPh[0], aPh[1], aPh[2], aPh[3]);
    const bf16x8 APl = mk_bf16x8(aPl[0], aPl[1], aPl[2], aPl[3]);
    const bf16x8 AQh = mk_bf16x8(aQh[0], aQh[1], aQh[2], aQh[3]);
    const bf16x8 AQl = mk_bf16x8(aQl[0], aQl[1], aQl[2], aQl[3]);

    const float bo_ = bias[o];
    float* op = out + (size_t)(b * 64 + o) * 16384;
#pragma unroll
    for (int n = 0; n < 8; ++n) {
      unsigned uph[4], upl[4], uqh[4], uql[4];
#pragma unroll
      for (int pr = 0; pr < 4; ++pr) {
        unsigned h0[2], l0[2], h1[2], l1[2];
#pragma unroll
        for (int h2 = 0; h2 < 2; ++h2) {
          int s = pr * 2 + h2;
          int ce = 16 * kg + 2 * s;
          int rP = ce > 60 ? 60 : ce;            // clamped (A slot is 0 there)
          int rQ = (ce + 1) > 60 ? 60 : ce + 1;  // clamped
          float uP = U[rP * 132 + n * 16 + mm];
          float uQ = U[rQ * 132 + n * 16 + mm];
          unsigned h = bf16_rne(uP);
          h0[h2] = h;
          l0[h2] = bf16_rne(uP - __uint_as_float(h << 16));
          h = bf16_rne(uQ);
          h1[h2] = h;
          l1[h2] = bf16_rne(uQ - __uint_as_float(h << 16));
        }
        uph[pr] = h0[0] | (h0[1] << 16);
        upl[pr] = l0[0] | (l0[1] << 16);
        uqh[pr] = h1[0] | (h1[1] << 16);
        uql[pr] = l1[0] | (l1[1] << 16);
      }
      bf16x8 UPh = mk_bf16x8(uph[0], uph[1], uph[2], uph[3]);
      bf16x8 UPl = mk_bf16x8(upl[0], upl[1], upl[2], upl[3]);
      bf16x8 UQh = mk_bf16x8(uqh[0], uqh[1], uqh[2], uqh[3]);
      bf16x8 UQl = mk_bf16x8(uql[0], uql[1], uql[2], uql[3]);
      f32x4 accP = {0.f, 0.f, 0.f, 0.f}, accQ = {0.f, 0.f, 0.f, 0.f};
      accP = __builtin_amdgcn_mfma_f32_16x16x32_bf16(APh, UPh, accP, 0, 0, 0);
      accP = __builtin_amdgcn_mfma_f32_16x16x32_bf16(APh, UPl, accP, 0, 0, 0);
      accP = __builtin_amdgcn_mfma_f32_16x16x32_bf16(APl, UPh, accP, 0, 0, 0);
      accQ = __builtin_amdgcn_mfma_f32_16x16x32_bf16(AQh, UQh, accQ, 0, 0, 0);
      accQ = __builtin_amdgcn_mfma_f32_16x16x32_bf16(AQh, UQl, accQ, 0, 0, 0);
      accQ = __builtin_amdgcn_mfma_f32_16x16x32_bf16(AQl, UQh, accQ, 0, 0, 0);
#pragma unroll
      for (int rr = 0; rr < 4; ++rr) {
        int y = wv * 16 + kg * 4 + rr;  // D row = (lane>>4)*4 + reg
        float p = accP[rr], qq = accQ[rr];
        op[y * 128 + n * 16 + mm] = p + qq + bo_;
        op[(y + 64) * 128 + n * 16 + mm] = p - qq + bo_;
      }
    }
  }
}

extern "C" void kernel_launch(void* const* d_in, const int* in_sizes, int n_in,
                              void* d_out, int out_size, void* d_ws, size_t ws_size,
                              hipStream_t stream) {
  (void)in_sizes; (void)n_in; (void)out_size; (void)ws_size;
  const float* x = (const float*)d_in[0];
  const float* w = (const float*)d_in[1];
  const float* bias = (const float*)d_in[2];
  float* out = (float*)d_out;

  unsigned* Wt = (unsigned*)d_ws;
  float* A = (float*)d_ws + 7745536;    // X2, later FT
  float* B = (float*)d_ws + 11618304;   // X2T, in-place F

  k012<<<2000, 256, 0, stream>>>(x, A, w, Wt);
  ktx<<<480, 256, 0, stream>>>((const float2*)A, (float2*)B);
  k3_mfma<<<946, 256, 0, stream>>>(B, Wt, B);
  ktf<<<480, 256, 0, stream>>>((const float2*)B, (float2*)A);
  k45_out<<<1024, 256, 0, stream>>>(A, bias, out);
}

// Round 12
// 214.878 us; speedup vs baseline: 1.5953x; 1.0228x over previous
//
#include <hip/hip_runtime.h>

// FFTConvNet: out[b,o] = IFFT2( M · sum_i X^[(b+8)%16, i] · W^[(o+32)%64, i] ) + bias[o]
// fftshift(no axes) shifts ALL dims -> batch roll 8, Cout roll 32; Cin rolls cancel.
// Disk mask fy^2+fx^2<=900. Half-spectrum: fy(t) in [0,30] (31), fx in [-30,30] (61), f2 = fxp*31+t.
// Pipeline: k012 (FUSED: blocks 0..1023 = fwd DFT -> X2 ; 1024..1999 = W^ bf16 frag-order) ;
//   ktx (X2 -> X2T[f2][i*16+b]) ; k3 (MFMA mix, in-place F) ; ktf (F -> FT[bo][f2]) ;
//   k45 (inverse: phase1 VALU inverse-x -> U ; phase2 MFMA GEMM).
// k12 Phase B is now MFMA too: per class r (= wave), Out[fxp][t] = sum_xx phase x Z as a
//   real-packed [16 x 64 x 32] GEMM, 2 K-steps x 2 N-tiles x (re,im) x 3-term bf16 split
//   = 24 MFMA/wave. k_flist's 4x16 section layout IS the M-tile. Same fragment convention
//   as k3/k45 (slot-pair packing chosen consistently on both operands).
// k12 Phase A: Cls = 4 planes x 1024 float2 = 32 KB exact, XOR swizzle slot = t ^ x ^ r.
// ws (62 MB): WtB u32 [0, 7745536) ; A = X2 / FT float [7745536, +3872768) ;
//             B = X2T / F float [11618304, +3872768).

#define PI2_128 0.04908738521234052f  // 2*pi/128
#define NF 1891

typedef __attribute__((ext_vector_type(8))) short bf16x8;
typedef __attribute__((ext_vector_type(4))) float f32x4;

// fxp list ordered by class r=(fxp+2)&3 (= fx mod 4): c0(15), c1(15), c2(16), c3(15), 3 dummies.
__device__ const int k_flist[64] = {
    2, 6, 10, 14, 18, 22, 26, 30, 34, 38, 42, 46, 50, 54, 58,
    3, 7, 11, 15, 19, 23, 27, 31, 35, 39, 43, 47, 51, 55, 59,
    0, 4, 8, 12, 16, 20, 24, 28, 32, 36, 40, 44, 48, 52, 56, 60,
    1, 5, 9, 13, 17, 21, 25, 29, 33, 37, 41, 45, 49, 53, 57,
    0, 0, 0};

__device__ inline unsigned bf16_rne(float v) {
  unsigned u = __float_as_uint(v);
  return (u + 0x7FFFu + ((u >> 16) & 1u)) >> 16;
}

__device__ inline bf16x8 mk_bf16x8(unsigned a, unsigned b, unsigned c, unsigned d) {
  union { unsigned u[4]; bf16x8 v; } x;
  x.u[0] = a; x.u[1] = b; x.u[2] = c; x.u[3] = d;
  return x.v;
}

// ---------------- K012: fused forward DFT (blocks 0..1023) + W^ precompute (1024..1999) ----
__global__ __launch_bounds__(256) void k012(const float* __restrict__ x,
                                            float* __restrict__ X2,
                                            const float* __restrict__ w,
                                            unsigned* __restrict__ Wt) {
  __shared__ __align__(16) float Cls[8192];
  const int tid = threadIdx.x;

  if (blockIdx.x < 1024) {
    // ================= k12: fwd DFT for image bi =================
    const int bi = blockIdx.x;
    const float* img = x + (size_t)bi * 16384;

    // Phase A: y-DFT, radix-4 fold over y.
    {
      const int tg = tid >> 5;  // 0..7
      const int xg = tid & 31;
      const int t_[4] = {4 * tg, 4 * tg + 2, 2 * tg + 1, 2 * tg + 17};  // t=31 discarded
      const float sgn = (tg & 1) ? 1.f : -1.f;  // (-i)^t for odd t
      float pc[4], ps[4], stc[4], sts[4];
#pragma unroll
      for (int f = 0; f < 4; ++f) {
        __sincosf((float)t_[f] * PI2_128, &sts[f], &stc[f]);
        pc[f] = 1.f;
        ps[f] = 0.f;
      }
      float ar_[4][4] = {{0.f}}, ai_[4][4] = {{0.f}};  // [freq][m]
      for (int y = 0; y < 32; ++y) {
        float v[4][4];
#pragma unroll
        for (int k = 0; k < 4; ++k)
#pragma unroll
          for (int m = 0; m < 4; ++m) v[k][m] = img[(y + 32 * k) * 128 + xg + 32 * m];
#pragma unroll
        for (int m = 0; m < 4; ++m) {
          float s = v[0][m] + v[2][m], d = v[0][m] - v[2][m];
          float s2 = v[1][m] + v[3][m], d2 = (v[1][m] - v[3][m]) * sgn;
          float a0 = s + s2, a1 = s - s2;
          ar_[0][m] += a0 * pc[0];
          ai_[0][m] -= a0 * ps[0];
          ar_[1][m] += a1 * pc[1];
          ai_[1][m] -= a1 * ps[1];
          ar_[2][m] += d * pc[2] + d2 * ps[2];
          ai_[2][m] += -d * ps[2] + d2 * pc[2];
          ar_[3][m] += d * pc[3] + d2 * ps[3];
          ai_[3][m] += -d * ps[3] + d2 * pc[3];
        }
#pragma unroll
        for (int f = 0; f < 4; ++f) {
          float c = pc[f], s = ps[f];
          pc[f] = c * stc[f] - s * sts[f];
          ps[f] = s * stc[f] + c * sts[f];
        }
      }
      // In-register x-butterfly; write 4 planes at swizzled slots.
      float2* Cf2 = (float2*)Cls;
#pragma unroll
      for (int f = 0; f < 4; ++f) {
        int t = t_[f];
        float Ar = ar_[f][0] + ar_[f][2], Ai = ai_[f][0] + ai_[f][2];
        float Br = ar_[f][0] - ar_[f][2], Bi = ai_[f][0] - ai_[f][2];
        float Cr = ar_[f][1] + ar_[f][3], Ci = ai_[f][1] + ai_[f][3];
        float Dr = ar_[f][1] - ar_[f][3], Di = ai_[f][1] - ai_[f][3];
        const int rowb = xg * 32;
        const int sx = t ^ xg;
        Cf2[0 * 1024 + rowb + (sx ^ 0)] = make_float2(Ar + Cr, Ai + Ci);  // r=0: A+C
        Cf2[1 * 1024 + rowb + (sx ^ 1)] = make_float2(Br + Di, Bi - Dr);  // r=1: B-iD
        Cf2[2 * 1024 + rowb + (sx ^ 2)] = make_float2(Ar - Cr, Ai - Ci);  // r=2: A-C
        Cf2[3 * 1024 + rowb + (sx ^ 3)] = make_float2(Br - Di, Bi + Dr);  // r=3: B+iD
      }
    }
    __syncthreads();

    // Phase B (MFMA): per class r (= wave wv), Out[fxp][t] = sum_xx phase(fxp,xx) * Z[r][xx][t].
    // Real-packed K = 2xx(re),2xx+1(im); A pair=(C,S) / im=(-S,C); B pair=(Zr,Zi).
    {
      const int wv = tid >> 6;  // class r
      const int lane = tid & 63;
      const int mm = lane & 15;  // A row (class member) during build; D col (t) at write
      const int kg = lane >> 4;  // k-group
      const int secS[4] = {0, 15, 30, 46};
      const int secC[4] = {15, 15, 16, 15};
      const int r = wv;
      const int cnt = secC[r];
      const int mc = mm < cnt ? mm : cnt - 1;  // clamp for dummy rows (output masked)
      const int fxpA = k_flist[secS[r] + mc];
      const float fx = (float)(fxpA - 30);

      unsigned ARh[2][4], ARl[2][4], AIh[2][4], AIl[2][4];
#pragma unroll
      for (int ks = 0; ks < 2; ++ks)
#pragma unroll
        for (int q = 0; q < 4; ++q) {
          int xx = ks * 16 + kg * 4 + q;
          float sv, cv;
          __sincosf(fx * (float)xx * PI2_128, &sv, &cv);
          unsigned ch = bf16_rne(cv), sh = bf16_rne(sv);
          float cl = cv - __uint_as_float(ch << 16);
          float sl = sv - __uint_as_float(sh << 16);
          unsigned chl = bf16_rne(cl), shl = bf16_rne(sl);
          ARh[ks][q] = ch | (sh << 16);
          ARl[ks][q] = chl | (shl << 16);
          AIh[ks][q] = (sh ^ 0x8000u) | (ch << 16);
          AIl[ks][q] = (shl ^ 0x8000u) | (chl << 16);
        }

      const float2* Cf2 = (const float2*)Cls;
      f32x4 accR0 = {0.f, 0.f, 0.f, 0.f}, accR1 = {0.f, 0.f, 0.f, 0.f};
      f32x4 accI0 = {0.f, 0.f, 0.f, 0.f}, accI1 = {0.f, 0.f, 0.f, 0.f};
#pragma unroll
      for (int ks = 0; ks < 2; ++ks) {
        bf16x8 Arh = mk_bf16x8(ARh[ks][0], ARh[ks][1], ARh[ks][2], ARh[ks][3]);
        bf16x8 Arl = mk_bf16x8(ARl[ks][0], ARl[ks][1], ARl[ks][2], ARl[ks][3]);
        bf16x8 Aih = mk_bf16x8(AIh[ks][0], AIh[ks][1], AIh[ks][2], AIh[ks][3]);
        bf16x8 Ail = mk_bf16x8(AIl[ks][0], AIl[ks][1], AIl[ks][2], AIl[ks][3]);
#pragma unroll
        for (int nt = 0; nt < 2; ++nt) {
          unsigned bh[4], bl[4];
#pragma unroll
          for (int q = 0; q < 4; ++q) {
            int xx = ks * 16 + kg * 4 + q;
            int t = nt * 16 + mm;
            float2 z = Cf2[r * 1024 + xx * 32 + (t ^ xx ^ r)];
            unsigned zrh = bf16_rne(z.x), zih = bf16_rne(z.y);
            float zrl = z.x - __uint_as_float(zrh << 16);
            float zil = z.y - __uint_as_float(zih << 16);
            bh[q] = zrh | (zih << 16);
            bl[q] = bf16_rne(zrl) | (bf16_rne(zil) << 16);
          }
          bf16x8 Bh = mk_bf16x8(bh[0], bh[1], bh[2], bh[3]);
          bf16x8 Bl = mk_bf16x8(bl[0], bl[1], bl[2], bl[3]);
          if (nt == 0) {
            accR0 = __builtin_amdgcn_mfma_f32_16x16x32_bf16(Arh, Bh, accR0, 0, 0, 0);
            accR0 = __builtin_amdgcn_mfma_f32_16x16x32_bf16(Arh, Bl, accR0, 0, 0, 0);
            accR0 = __builtin_amdgcn_mfma_f32_16x16x32_bf16(Arl, Bh, accR0, 0, 0, 0);
            accI0 = __builtin_amdgcn_mfma_f32_16x16x32_bf16(Aih, Bh, accI0, 0, 0, 0);
            accI0 = __builtin_amdgcn_mfma_f32_16x16x32_bf16(Aih, Bl, accI0, 0, 0, 0);
            accI0 = __builtin_amdgcn_mfma_f32_16x16x32_bf16(Ail, Bh, accI0, 0, 0, 0);
          } else {
            accR1 = __builtin_amdgcn_mfma_f32_16x16x32_bf16(Arh, Bh, accR1, 0, 0, 0);
            accR1 = __builtin_amdgcn_mfma_f32_16x16x32_bf16(Arh, Bl, accR1, 0, 0, 0);
            accR1 = __builtin_amdgcn_mfma_f32_16x16x32_bf16(Arl, Bh, accR1, 0, 0, 0);
            accI1 = __builtin_amdgcn_mfma_f32_16x16x32_bf16(Aih, Bh, accI1, 0, 0, 0);
            accI1 = __builtin_amdgcn_mfma_f32_16x16x32_bf16(Aih, Bl, accI1, 0, 0, 0);
            accI1 = __builtin_amdgcn_mfma_f32_16x16x32_bf16(Ail, Bh, accI1, 0, 0, 0);
          }
        }
      }

      // D: row = kg*4+rr = class member, col = mm = t (within nt tile). Mask dummies/t>30/disk.
      float2* X2c = (float2*)X2 + (size_t)bi * NF;
#pragma unroll
      for (int nt = 0; nt < 2; ++nt)
#pragma unroll
        for (int rr = 0; rr < 4; ++rr) {
          int mp = kg * 4 + rr;
          int t = nt * 16 + mm;
          if (mp < cnt && t <= 30) {
            int fxpw = k_flist[secS[r] + mp];
            int fxv = fxpw - 30;
            bool keep = (t * t + fxv * fxv) <= 900;
            float re = nt == 0 ? accR0[rr] : accR1[rr];
            float im = nt == 0 ? accI0[rr] : accI1[rr];
            X2c[fxpw * 31 + t] = keep ? make_float2(re, im) : make_float2(0.f, 0.f);
          }
        }
    }
  } else {
    // ================= k0: W^ precompute (bf16), separable 3x3 twiddles =================
    const int bid2 = (int)blockIdx.x - 1024;
    const int fxp = bid2 >> 4;  // 0..60
    const int ig = bid2 & 15;
    const int il = tid & 3;
    const int o = ((tid >> 5) << 3) | ((tid >> 2) & 7);
    const int i = ig * 4 + il;
    const int op = (o + 32) & 63;
    const float* wp = w + (size_t)(op * 64 + i) * 9;
    float w9[9];
#pragma unroll
    for (int k = 0; k < 9; ++k) w9[k] = wp[k];

    const float fx = (float)(fxp - 30);
    float sn, cs;
    __sincosf(fx * PI2_128, &sn, &cs);
    const float e1x = cs, e1y = -sn;
    const float e2x = e1x * e1x - e1y * e1y, e2y = 2.f * e1x * e1y;
    float rxr[3], rxi[3];
#pragma unroll
    for (int ky = 0; ky < 3; ++ky) {
      rxr[ky] = w9[ky * 3] + w9[ky * 3 + 1] * e1x + w9[ky * 3 + 2] * e2x;
      rxi[ky] = w9[ky * 3 + 1] * e1y + w9[ky * 3 + 2] * e2y;
    }
    float pyx = 1.f, pyy = 0.f;
    const float stx = 0.9987954562f, sty = -0.04906767433f;
    unsigned* Wb = Wt + (size_t)(fxp * 31) * 4096 + (o >> 3) * 512 + (i >> 4) * 128 +
                   (((i >> 2) & 3) * 8 + (o & 7)) * 4 + (i & 3);
    for (int fy = 0; fy < 31; ++fy) {
      float p2x = pyx * pyx - pyy * pyy, p2y = 2.f * pyx * pyy;
      float Wre = rxr[0] + (rxr[1] * pyx - rxi[1] * pyy) + (rxr[2] * p2x - rxi[2] * p2y);
      float Wim = rxi[0] + (rxr[1] * pyy + rxi[1] * pyx) + (rxr[2] * p2y + rxi[2] * p2x);
      Wb[(size_t)fy * 4096] = bf16_rne(Wre) | (bf16_rne(Wim) << 16);
      float nx = pyx * stx - pyy * sty;
      pyy = pyx * sty + pyy * stx;
      pyx = nx;
    }
  }
}

// ---------------- KTX: X2[bi][f2] -> X2T[f2][i*16+b]  (64x64 float2 LDS tiles) ------
__global__ __launch_bounds__(256) void ktx(const float2* __restrict__ X2,
                                           float2* __restrict__ X2T) {
  __shared__ __align__(16) float2 Ld[4096];
  const int tid = threadIdx.x;
  const int tf = blockIdx.x % 30;  // f2 tile
  const int tc = blockIdx.x / 30;  // out-col tile: i0 = tc*4
  const int f2_0 = tf * 64;
  const int lo = tid & 63, hi = tid >> 6;
#pragma unroll
  for (int k = 0; k < 16; ++k) {
    int c = k * 4 + hi;  // local out-col: c = (i-i0)*16 + b
    int bi = (c & 15) * 64 + tc * 4 + (c >> 4);
    int f2 = f2_0 + lo;
    float2 v = (f2 < NF) ? X2[(size_t)bi * NF + f2] : make_float2(0.f, 0.f);
    Ld[(c << 6) | (lo ^ c)] = v;  // XOR-swizzled: conflict-free both phases
  }
  __syncthreads();
#pragma unroll
  for (int k = 0; k < 16; ++k) {
    int fr = k * 4 + hi;
    int f2 = f2_0 + fr;
    if (f2 < NF) X2T[(size_t)f2 * 1024 + tc * 64 + lo] = Ld[(lo << 6) | (fr ^ lo)];
  }
}

// ---------------- K3: per-frequency channel mix via MFMA (bf16, X split hi/lo) ----
__global__ __launch_bounds__(256) void k3_mfma(const float* X2T,
                                               const unsigned* __restrict__ WtB,
                                               float* F) {
  // bijective XCD-chunked blockIdx swizzle (m204 form)
  const int nwg = (int)gridDim.x;
  const int orig = (int)blockIdx.x;
  const int xcd = orig & 7;
  const int q = nwg >> 3, r = nwg & 7;
  const int blk = (xcd < r ? xcd * (q + 1) : r * (q + 1) + (xcd - r) * q) + (orig >> 3);

  const int tid = (int)threadIdx.x;
  const int wv = tid >> 6;
  const int g = blk * 4 + wv;
  const int f2v = g >> 1;
  const bool valid = f2v < NF;
  const int f2 = valid ? f2v : NF - 1;  // clamp keeps reads in the block's own rows
  const int half = g & 1;
  const int lane = tid & 63;
  const int m = lane & 15;   // A-row (output batch) == B-col-within-tile
  const int lg = lane >> 4;  // k lane-group
  const int bs = (m + 8) & 15;
  const int co = m & 1;      // re/im column parity

  // ---- A: gather X2T row f2 (coalesced); i = ks*16 + lg*4 + t ----
  float2 xv[4][4];
  const float2* Xc = (const float2*)X2T;
#pragma unroll
  for (int ks = 0; ks < 4; ++ks)
#pragma unroll
    for (int t = 0; t < 4; ++t)
      xv[ks][t] = Xc[(size_t)f2 * 1024 + (ks * 16 + lg * 4 + t) * 16 + bs];

  __syncthreads();  // all waves done reading their rows before any in-place store

  unsigned ahi[4][4], alo[4][4];
#pragma unroll
  for (int ks = 0; ks < 4; ++ks) {
#pragma unroll
    for (int t = 0; t < 4; ++t) {
      float xr = xv[ks][t].x, xi = xv[ks][t].y;
      unsigned hr = bf16_rne(xr), hi2 = bf16_rne(xi);
      float lr = xr - __uint_as_float(hr << 16);
      float li = xi - __uint_as_float(hi2 << 16);
      ahi[ks][t] = hr | (hi2 << 16);
      alo[ks][t] = bf16_rne(lr) | (bf16_rne(li) << 16);
    }
  }

  f32x4 acc[4];
#pragma unroll
  for (int nt = 0; nt < 4; ++nt) acc[nt] = {0.f, 0.f, 0.f, 0.f};

  const unsigned* Wb =
      WtB + (size_t)f2 * 4096 + half * 2048 + (lg * 8 + (m >> 1)) * 4;
#pragma unroll
  for (int ks = 0; ks < 4; ++ks) {
    bf16x8 bfr[4];
#pragma unroll
    for (int nt = 0; nt < 4; ++nt) {
      uint4 wq = *(const uint4*)(Wb + nt * 512 + ks * 128);
      unsigned b0, b1, b2, b3;
      if (co) {  // odd col: (Wi, Wr) = rot16(w)
        b0 = (wq.x >> 16) | (wq.x << 16);
        b1 = (wq.y >> 16) | (wq.y << 16);
        b2 = (wq.z >> 16) | (wq.z << 16);
        b3 = (wq.w >> 16) | (wq.w << 16);
      } else {   // even col: (Wr, -Wi) = w ^ signbit(hi)
        b0 = wq.x ^ 0x80000000u;
        b1 = wq.y ^ 0x80000000u;
        b2 = wq.z ^ 0x80000000u;
        b3 = wq.w ^ 0x80000000u;
      }
      bfr[nt] = mk_bf16x8(b0, b1, b2, b3);
    }
    bf16x8 ah = mk_bf16x8(ahi[ks][0], ahi[ks][1], ahi[ks][2], ahi[ks][3]);
    bf16x8 al = mk_bf16x8(alo[ks][0], alo[ks][1], alo[ks][2], alo[ks][3]);
#pragma unroll
    for (int nt = 0; nt < 4; ++nt)
      acc[nt] = __builtin_amdgcn_mfma_f32_16x16x32_bf16(ah, bfr[nt], acc[nt], 0, 0, 0);
#pragma unroll
    for (int nt = 0; nt < 4; ++nt)
      acc[nt] = __builtin_amdgcn_mfma_f32_16x16x32_bf16(al, bfr[nt], acc[nt], 0, 0, 0);
  }

  if (valid) {
    float* Fo = F + (size_t)f2 * 2048 + half * 64 + m;
#pragma unroll
    for (int nt = 0; nt < 4; ++nt)
#pragma unroll
      for (int rr = 0; rr < 4; ++rr)
        Fo[(lg * 4 + rr) * 128 + nt * 16] = acc[nt][rr];
  }
}

// ---------------- KTF: F[f2][bo] -> FT[bo][f2]  (64x64 float2 LDS tiles) -----------
__global__ __launch_bounds__(256) void ktf(const float2* __restrict__ F2,
                                           float2* __restrict__ FT) {
  __shared__ __align__(16) float2 Ld[4096];
  const int tid = threadIdx.x;
  const int tf = blockIdx.x % 30;
  const int tc = blockIdx.x / 30;
  const int f2_0 = tf * 64, c0 = tc * 64;
  const int lo = tid & 63, hi = tid >> 6;
#pragma unroll
  for (int k = 0; k < 16; ++k) {
    int fr = k * 4 + hi;
    int f2 = f2_0 + fr;
    float2 v = (f2 < NF) ? F2[(size_t)f2 * 1024 + c0 + lo] : make_float2(0.f, 0.f);
    Ld[(fr << 6) | (lo ^ fr)] = v;
  }
  __syncthreads();
#pragma unroll
  for (int k = 0; k < 16; ++k) {
    int cc = k * 4 + hi;
    int f2 = f2_0 + lo;
    if (f2 < NF) FT[(size_t)(c0 + cc) * NF + f2] = Ld[(lo << 6) | (cc ^ lo)];
  }
}

// ---------------- K45: inverse (radix-4 fold in x) + MFMA inverse-y + bias ----------
__global__ __launch_bounds__(256) void k45_out(const float* __restrict__ FT,
                                               const float* __restrict__ bias,
                                               float* __restrict__ out) {
  __shared__ __align__(16) float2 tw[128];  // e^{+2pi i m/128}
  __shared__ __align__(16) float U[61 * 132];
  __shared__ __align__(16) float TF[3904];  // Fl staging (phase 1 only)
  const int b = blockIdx.x >> 6;
  const int o = blockIdx.x & 63;
  const int tid = threadIdx.x;
  float2* Fl = (float2*)TF;
  // FT layout [bo][NF] -> contiguous row load.
  const float2* Fc = (const float2*)FT + (size_t)(b * 64 + o) * NF;
  if (tid < 128) {
    float sv, cv;
    __sincosf((float)tid * PI2_128, &sv, &cv);
    tw[tid] = make_float2(cv, sv);
  }
  for (int j = tid; j < NF; j += 256) Fl[j] = Fc[j];
  __syncthreads();

  // Phase 1: inverse-x with output fold H(x+32k) = sum_r i^{rk} S_r
  {
    const int fy = tid & 31;
    const int xg = tid >> 3 >> 2;  // tid>>5: 0..7
    if (fy < 31) {
      float Sr[4][4] = {{0.f}}, Si[4][4] = {{0.f}};  // [r][j]
      float pr[4], pi[4], cr[4], ci[4];
#pragma unroll
      for (int j = 0; j < 4; ++j) {
        int xj = 4 * xg + j;
        float2 st = tw[xj];
        cr[j] = st.x;
        ci[j] = st.y;
        float2 p0 = tw[(-30 * xj) & 127];
        pr[j] = p0.x;
        pi[j] = p0.y;
      }
      const float2* Frow = Fl + fy;
      for (int f4 = 0; f4 < 60; f4 += 4) {
#pragma unroll
        for (int ss = 0; ss < 4; ++ss) {
          const int r = (ss + 2) & 3;  // fxp class pattern 2,3,0,1
          float2 fv = Frow[(f4 + ss) * 31];
#pragma unroll
          for (int j = 0; j < 4; ++j) {
            Sr[r][j] += fv.x * pr[j] - fv.y * pi[j];
            Si[r][j] += fv.x * pi[j] + fv.y * pr[j];
            float np = pr[j] * cr[j] - pi[j] * ci[j];
            pi[j] = pi[j] * cr[j] + pr[j] * ci[j];
            pr[j] = np;
          }
        }
      }
      {  // fxp = 60, class 2
        float2 fv = Frow[60 * 31];
#pragma unroll
        for (int j = 0; j < 4; ++j) {
          Sr[2][j] += fv.x * pr[j] - fv.y * pi[j];
          Si[2][j] += fv.x * pi[j] + fv.y * pr[j];
        }
      }
#pragma unroll
      for (int j = 0; j < 4; ++j) {
        int xj = 4 * xg + j;
        float Er = Sr[0][j] + Sr[2][j], Ei = Si[0][j] + Si[2][j];
        float Fr = Sr[0][j] - Sr[2][j], Fi = Si[0][j] - Si[2][j];
        float Gr = Sr[1][j] + Sr[3][j], Gi = Si[1][j] + Si[3][j];
        float Hr = Sr[1][j] - Sr[3][j], Hi = Si[1][j] - Si[3][j];
        U[fy * 132 + xj] = Er + Gr;
        U[fy * 132 + xj + 32] = Fr - Hi;   // F4 + iH
        U[fy * 132 + xj + 64] = Er - Gr;
        U[fy * 132 + xj + 96] = Fr + Hi;   // F4 - iH
        if (fy >= 1) {
          U[(30 + fy) * 132 + xj] = Ei + Gi;
          U[(30 + fy) * 132 + xj + 32] = Fi + Hr;
          U[(30 + fy) * 132 + xj + 64] = Ei - Gi;
          U[(30 + fy) * 132 + xj + 96] = Fi - Hr;
        }
      }
    }
  }
  __syncthreads();

  // Phase 2 (MFMA): out rows y (M=64) x cols x (N=128). P = even-c GEMM, Q = odd-c GEMM,
  // K=32 (one MFMA step). A = T on-the-fly from tw; B = U from LDS. 3-term bf16 hi/lo split.
  {
    const int wv = tid >> 6;       // wave -> y-tile
    const int lane = tid & 63;
    const int mm = lane & 15;
    const int kg = lane >> 4;      // k-group
    const int yA = wv * 16 + mm;   // A-frag row (y)
    const float sc1 = 1.f / 16384.f;

    unsigned aPh[4], aPl[4], aQh[4], aQl[4];
#pragma unroll
    for (int pr = 0; pr < 4; ++pr) {
      unsigned hP[2], lP[2], hQ[2], lQ[2];
#pragma unroll
      for (int h2 = 0; h2 < 2; ++h2) {
        int s = pr * 2 + h2;
        int ce = 16 * kg + 2 * s;  // even c for P
        int co = ce + 1;           // odd c for Q
        float vP, vQ;
        if (ce == 0) vP = sc1;
        else if (ce <= 30) vP = 2.f * sc1 * tw[(ce * yA) & 127].x;
        else if (ce <= 60) vP = -2.f * sc1 * tw[((ce - 30) * yA) & 127].y;
        else vP = 0.f;
        if (co <= 30) vQ = 2.f * sc1 * tw[(co * yA) & 127].x;
        else if (co <= 59) vQ = -2.f * sc1 * tw[((co - 30) * yA) & 127].y;
        else vQ = 0.f;
        unsigned h = bf16_rne(vP);
        hP[h2] = h;
        lP[h2] = bf16_rne(vP - __uint_as_float(h << 16));
        h = bf16_rne(vQ);
        hQ[h2] = h;
        lQ[h2] = bf16_rne(vQ - __uint_as_float(h << 16));
      }
      aPh[pr] = hP[0] | (hP[1] << 16);
      aPl[pr] = lP[0] | (lP[1] << 16);
      aQh[pr] = hQ[0] | (hQ[1] << 16);
      aQl[pr] = lQ[0] | (lQ[1] << 16);
    }
    const bf16x8 APh = mk_bf16x8(aPh[0], aPh[1], aPh[2], aPh[3]);
    const bf16x8 APl = mk_bf16x8(aPl[0], aPl[1], aPl[2], aPl[3]);
    const bf16x8 AQh = mk_bf16x8(aQh[0], aQh[1], aQh[2], aQh[3]);
    const bf16x8 AQl = mk_bf16x8(aQl[0], aQl[1], aQl[2], aQl[3]);

    const float bo_ = bias[o];
    float* op = out + (size_t)(b * 64 + o) * 16384;
#pragma unroll
    for (int n = 0; n < 8; ++n) {
      unsigned uph[4], upl[4], uqh[4], uql[4];
#pragma unroll
      for (int pr = 0; pr < 4; ++pr) {
        unsigned h0[2], l0[2], h1[2], l1[2];
#pragma unroll
        for (int h2 = 0; h2 < 2; ++h2) {
          int s = pr * 2 + h2;
          int ce = 16 * kg + 2 * s;
          int rP = ce > 60 ? 60 : ce;            // clamped (A slot is 0 there)
          int rQ = (ce + 1) > 60 ? 60 : ce + 1;  // clamped
          float uP = U[rP * 132 + n * 16 + mm];
          float uQ = U[rQ * 132 + n * 16 + mm];
          unsigned h = bf16_rne(uP);
          h0[h2] = h;
          l0[h2] = bf16_rne(uP - __uint_as_float(h << 16));
          h = bf16_rne(uQ);
          h1[h2] = h;
          l1[h2] = bf16_rne(uQ - __uint_as_float(h << 16));
        }
        uph[pr] = h0[0] | (h0[1] << 16);
        upl[pr] = l0[0] | (l0[1] << 16);
        uqh[pr] = h1[0] | (h1[1] << 16);
        uql[pr] = l1[0] | (l1[1] << 16);
      }
      bf16x8 UPh = mk_bf16x8(uph[0], uph[1], uph[2], uph[3]);
      bf16x8 UPl = mk_bf16x8(upl[0], upl[1], upl[2], upl[3]);
      bf16x8 UQh = mk_bf16x8(uqh[0], uqh[1], uqh[2], uqh[3]);
      bf16x8 UQl = mk_bf16x8(uql[0], uql[1], uql[2], uql[3]);
      f32x4 accP = {0.f, 0.f, 0.f, 0.f}, accQ = {0.f, 0.f, 0.f, 0.f};
      accP = __builtin_amdgcn_mfma_f32_16x16x32_bf16(APh, UPh, accP, 0, 0, 0);
      accP = __builtin_amdgcn_mfma_f32_16x16x32_bf16(APh, UPl, accP, 0, 0, 0);
      accP = __builtin_amdgcn_mfma_f32_16x16x32_bf16(APl, UPh, accP, 0, 0, 0);
      accQ = __builtin_amdgcn_mfma_f32_16x16x32_bf16(AQh, UQh, accQ, 0, 0, 0);
      accQ = __builtin_amdgcn_mfma_f32_16x16x32_bf16(AQh, UQl, accQ, 0, 0, 0);
      accQ = __builtin_amdgcn_mfma_f32_16x16x32_bf16(AQl, UQh, accQ, 0, 0, 0);
#pragma unroll
      for (int rr = 0; rr < 4; ++rr) {
        int y = wv * 16 + kg * 4 + rr;  // D row = (lane>>4)*4 + reg
        float p = accP[rr], qq = accQ[rr];
        op[y * 128 + n * 16 + mm] = p + qq + bo_;
        op[(y + 64) * 128 + n * 16 + mm] = p - qq + bo_;
      }
    }
  }
}

extern "C" void kernel_launch(void* const* d_in, const int* in_sizes, int n_in,
                              void* d_out, int out_size, void* d_ws, size_t ws_size,
                              hipStream_t stream) {
  (void)in_sizes; (void)n_in; (void)out_size; (void)ws_size;
  const float* x = (const float*)d_in[0];
  const float* w = (const float*)d_in[1];
  const float* bias = (const float*)d_in[2];
  float* out = (float*)d_out;

  unsigned* Wt = (unsigned*)d_ws;
  float* A = (float*)d_ws + 7745536;    // X2, later FT
  float* B = (float*)d_ws + 11618304;   // X2T, in-place F

  k012<<<2000, 256, 0, stream>>>(x, A, w, Wt);
  ktx<<<480, 256, 0, stream>>>((const float2*)A, (float2*)B);
  k3_mfma<<<946, 256, 0, stream>>>(B, Wt, B);
  ktf<<<480, 256, 0, stream>>>((const float2*)B, (float2*)A);
  k45_out<<<1024, 256, 0, stream>>>(A, bias, out);
}

// Round 13
// 203.380 us; speedup vs baseline: 1.6855x; 1.0565x over previous
//
#include <hip/hip_runtime.h>

// FFTConvNet: out[b,o] = IFFT2( M · sum_i X^[(b+8)%16, i] · W^[(o+32)%64, i] ) + bias[o]
// fftshift(no axes) shifts ALL dims -> batch roll 8, Cout roll 32; Cin rolls cancel.
// Disk mask fy^2+fx^2<=900. Half-spectrum: fy(t) in [0,30] (31), fx in [-30,30] (61), f2 = fxp*31+t.
// Pipeline: k012 (FUSED: blocks 0..1023 = fwd DFT -> X2 ; 1024..1999 = W^ bf16 frag-order) ;
//   ktx (X2 -> X2T[f2][i*16+b]) ; k3 (MFMA mix, in-place F) ; ktf (F -> FT[bo][f2]) ;
//   k45 (inverse: phase1 VALU inverse-x -> U ; phase2 MFMA GEMM).
// k12 Phase A v5: float4 loads (x = 4*xg+j contiguous; 128 VMEM/thread vs 512 scalar),
//   radix-4 x-butterfly via shfl_xor(16), shfl_xor(8); lane group mg=xg>>3 -> plane r {0,2,1,3}.
//   Cls layout unchanged: float2 plane[r][xloc][slot], slot = t ^ xloc ^ r (32 KB exact).
// k12 Phase B: MFMA per class r (= wave): real-packed [16 x 64 x 32] GEMM, 24 MFMA/wave.
// ws (62 MB): WtB u32 [0, 7745536) ; A = X2 / FT float [7745536, +3872768) ;
//             B = X2T / F float [11618304, +3872768).

#define PI2_128 0.04908738521234052f  // 2*pi/128
#define NF 1891

typedef __attribute__((ext_vector_type(8))) short bf16x8;
typedef __attribute__((ext_vector_type(4))) float f32x4;

// fxp list ordered by class r=(fxp+2)&3 (= fx mod 4): c0(15), c1(15), c2(16), c3(15), 3 dummies.
__device__ const int k_flist[64] = {
    2, 6, 10, 14, 18, 22, 26, 30, 34, 38, 42, 46, 50, 54, 58,
    3, 7, 11, 15, 19, 23, 27, 31, 35, 39, 43, 47, 51, 55, 59,
    0, 4, 8, 12, 16, 20, 24, 28, 32, 36, 40, 44, 48, 52, 56, 60,
    1, 5, 9, 13, 17, 21, 25, 29, 33, 37, 41, 45, 49, 53, 57,
    0, 0, 0};

__device__ inline unsigned bf16_rne(float v) {
  unsigned u = __float_as_uint(v);
  return (u + 0x7FFFu + ((u >> 16) & 1u)) >> 16;
}

__device__ inline bf16x8 mk_bf16x8(unsigned a, unsigned b, unsigned c, unsigned d) {
  union { unsigned u[4]; bf16x8 v; } x;
  x.u[0] = a; x.u[1] = b; x.u[2] = c; x.u[3] = d;
  return x.v;
}

// ---------------- K012: fused forward DFT (blocks 0..1023) + W^ precompute (1024..1999) ----
__global__ __launch_bounds__(256) void k012(const float* __restrict__ x,
                                            float* __restrict__ X2,
                                            const float* __restrict__ w,
                                            unsigned* __restrict__ Wt) {
  __shared__ __align__(16) float Cls[8192];
  const int tid = threadIdx.x;

  if (blockIdx.x < 1024) {
    // ================= k12: fwd DFT for image bi =================
    const int bi = blockIdx.x;
    const float* img = x + (size_t)bi * 16384;

    // Phase A: y-DFT (radix-4 fold over y), float4 loads, shfl-based x-butterfly.
    {
      const int tg = tid >> 5;  // 0..7
      const int xg = tid & 31;
      const int t_[4] = {4 * tg, 4 * tg + 2, 2 * tg + 1, 2 * tg + 17};  // t=31 discarded
      const float sgn = (tg & 1) ? 1.f : -1.f;  // (-i)^t for odd t
      float pc[4], ps[4], stc[4], sts[4];
#pragma unroll
      for (int f = 0; f < 4; ++f) {
        __sincosf((float)t_[f] * PI2_128, &sts[f], &stc[f]);
        pc[f] = 1.f;
        ps[f] = 0.f;
      }
      float ar_[4][4] = {{0.f}}, ai_[4][4] = {{0.f}};  // [freq][j], x = 4*xg + j
      for (int y = 0; y < 32; ++y) {
        const float* p = img + y * 128 + 4 * xg;
        float4 v0 = *(const float4*)(p);
        float4 v1 = *(const float4*)(p + 32 * 128);
        float4 v2 = *(const float4*)(p + 64 * 128);
        float4 v3 = *(const float4*)(p + 96 * 128);
        float a0v[4] = {v0.x, v0.y, v0.z, v0.w};
        float a1v[4] = {v1.x, v1.y, v1.z, v1.w};
        float a2v[4] = {v2.x, v2.y, v2.z, v2.w};
        float a3v[4] = {v3.x, v3.y, v3.z, v3.w};
#pragma unroll
        for (int j = 0; j < 4; ++j) {
          float s = a0v[j] + a2v[j], d = a0v[j] - a2v[j];
          float s2 = a1v[j] + a3v[j], d2 = (a1v[j] - a3v[j]) * sgn;
          float a0 = s + s2, a1 = s - s2;
          ar_[0][j] += a0 * pc[0];
          ai_[0][j] -= a0 * ps[0];
          ar_[1][j] += a1 * pc[1];
          ai_[1][j] -= a1 * ps[1];
          ar_[2][j] += d * pc[2] + d2 * ps[2];
          ai_[2][j] += -d * ps[2] + d2 * pc[2];
          ar_[3][j] += d * pc[3] + d2 * ps[3];
          ai_[3][j] += -d * ps[3] + d2 * pc[3];
        }
#pragma unroll
        for (int f = 0; f < 4; ++f) {
          float c = pc[f], s = ps[f];
          pc[f] = c * stc[f] - s * sts[f];
          ps[f] = s * stc[f] + c * sts[f];
        }
      }
      // x-butterfly across lanes (partners xg^8, xg^16); lane group mg -> plane r {0,2,1,3}.
      float2* Cf2 = (float2*)Cls;
      const int xl = xg & 7;
      const bool b3 = (xg & 8) != 0;
      const bool b4 = (xg & 16) != 0;
      const int r = b3 ? (b4 ? 3 : 2) : (b4 ? 1 : 0);
#pragma unroll
      for (int f = 0; f < 4; ++f) {
        int t = t_[f];
#pragma unroll
        for (int j = 0; j < 4; ++j) {
          float zr = ar_[f][j], zi = ai_[f][j];
          float br = __shfl_xor(zr, 16), bi2 = __shfl_xor(zi, 16);
          float s1r = b4 ? (br - zr) : (zr + br);
          float s1i = b4 ? (bi2 - zi) : (zi + bi2);
          float pr2 = __shfl_xor(s1r, 8), pi2 = __shfl_xor(s1i, 8);
          float c1 = b4 ? (s1r + pi2) : (s1r + pr2);
          float c2 = b4 ? (pr2 - s1i) : (pr2 - s1r);
          float fr = b3 ? c2 : c1;
          float d1 = b4 ? (s1i - pr2) : (s1i + pi2);
          float d2_ = b4 ? (pi2 + s1r) : (pi2 - s1i);
          float fi = b3 ? d2_ : d1;
          int xloc = 4 * xl + j;
          Cf2[r * 1024 + xloc * 32 + (t ^ xloc ^ r)] = make_float2(fr, fi);
        }
      }
    }
    __syncthreads();

    // Phase B (MFMA): per class r (= wave wv), Out[fxp][t] = sum_xx phase(fxp,xx) * Z[r][xx][t].
    // Real-packed K = 2xx(re),2xx+1(im); A pair=(C,S) / im=(-S,C); B pair=(Zr,Zi).
    {
      const int wv = tid >> 6;  // class r
      const int lane = tid & 63;
      const int mm = lane & 15;  // A row (class member) during build; D col (t) at write
      const int kg = lane >> 4;  // k-group
      const int secS[4] = {0, 15, 30, 46};
      const int secC[4] = {15, 15, 16, 15};
      const int r = wv;
      const int cnt = secC[r];
      const int mc = mm < cnt ? mm : cnt - 1;  // clamp for dummy rows (output masked)
      const int fxpA = k_flist[secS[r] + mc];
      const float fx = (float)(fxpA - 30);

      unsigned ARh[2][4], ARl[2][4], AIh[2][4], AIl[2][4];
#pragma unroll
      for (int ks = 0; ks < 2; ++ks)
#pragma unroll
        for (int q = 0; q < 4; ++q) {
          int xx = ks * 16 + kg * 4 + q;
          float sv, cv;
          __sincosf(fx * (float)xx * PI2_128, &sv, &cv);
          unsigned ch = bf16_rne(cv), sh = bf16_rne(sv);
          float cl = cv - __uint_as_float(ch << 16);
          float sl = sv - __uint_as_float(sh << 16);
          unsigned chl = bf16_rne(cl), shl = bf16_rne(sl);
          ARh[ks][q] = ch | (sh << 16);
          ARl[ks][q] = chl | (shl << 16);
          AIh[ks][q] = (sh ^ 0x8000u) | (ch << 16);
          AIl[ks][q] = (shl ^ 0x8000u) | (chl << 16);
        }

      const float2* Cf2 = (const float2*)Cls;
      f32x4 accR0 = {0.f, 0.f, 0.f, 0.f}, accR1 = {0.f, 0.f, 0.f, 0.f};
      f32x4 accI0 = {0.f, 0.f, 0.f, 0.f}, accI1 = {0.f, 0.f, 0.f, 0.f};
#pragma unroll
      for (int ks = 0; ks < 2; ++ks) {
        bf16x8 Arh = mk_bf16x8(ARh[ks][0], ARh[ks][1], ARh[ks][2], ARh[ks][3]);
        bf16x8 Arl = mk_bf16x8(ARl[ks][0], ARl[ks][1], ARl[ks][2], ARl[ks][3]);
        bf16x8 Aih = mk_bf16x8(AIh[ks][0], AIh[ks][1], AIh[ks][2], AIh[ks][3]);
        bf16x8 Ail = mk_bf16x8(AIl[ks][0], AIl[ks][1], AIl[ks][2], AIl[ks][3]);
#pragma unroll
        for (int nt = 0; nt < 2; ++nt) {
          unsigned bh[4], bl[4];
#pragma unroll
          for (int q = 0; q < 4; ++q) {
            int xx = ks * 16 + kg * 4 + q;
            int t = nt * 16 + mm;
            float2 z = Cf2[r * 1024 + xx * 32 + (t ^ xx ^ r)];
            unsigned zrh = bf16_rne(z.x), zih = bf16_rne(z.y);
            float zrl = z.x - __uint_as_float(zrh << 16);
            float zil = z.y - __uint_as_float(zih << 16);
            bh[q] = zrh | (zih << 16);
            bl[q] = bf16_rne(zrl) | (bf16_rne(zil) << 16);
          }
          bf16x8 Bh = mk_bf16x8(bh[0], bh[1], bh[2], bh[3]);
          bf16x8 Bl = mk_bf16x8(bl[0], bl[1], bl[2], bl[3]);
          if (nt == 0) {
            accR0 = __builtin_amdgcn_mfma_f32_16x16x32_bf16(Arh, Bh, accR0, 0, 0, 0);
            accR0 = __builtin_amdgcn_mfma_f32_16x16x32_bf16(Arh, Bl, accR0, 0, 0, 0);
            accR0 = __builtin_amdgcn_mfma_f32_16x16x32_bf16(Arl, Bh, accR0, 0, 0, 0);
            accI0 = __builtin_amdgcn_mfma_f32_16x16x32_bf16(Aih, Bh, accI0, 0, 0, 0);
            accI0 = __builtin_amdgcn_mfma_f32_16x16x32_bf16(Aih, Bl, accI0, 0, 0, 0);
            accI0 = __builtin_amdgcn_mfma_f32_16x16x32_bf16(Ail, Bh, accI0, 0, 0, 0);
          } else {
            accR1 = __builtin_amdgcn_mfma_f32_16x16x32_bf16(Arh, Bh, accR1, 0, 0, 0);
            accR1 = __builtin_amdgcn_mfma_f32_16x16x32_bf16(Arh, Bl, accR1, 0, 0, 0);
            accR1 = __builtin_amdgcn_mfma_f32_16x16x32_bf16(Arl, Bh, accR1, 0, 0, 0);
            accI1 = __builtin_amdgcn_mfma_f32_16x16x32_bf16(Aih, Bh, accI1, 0, 0, 0);
            accI1 = __builtin_amdgcn_mfma_f32_16x16x32_bf16(Aih, Bl, accI1, 0, 0, 0);
            accI1 = __builtin_amdgcn_mfma_f32_16x16x32_bf16(Ail, Bh, accI1, 0, 0, 0);
          }
        }
      }

      // D: row = kg*4+rr = class member, col = mm = t (within nt tile). Mask dummies/t>30/disk.
      float2* X2c = (float2*)X2 + (size_t)bi * NF;
#pragma unroll
      for (int nt = 0; nt < 2; ++nt)
#pragma unroll
        for (int rr = 0; rr < 4; ++rr) {
          int mp = kg * 4 + rr;
          int t = nt * 16 + mm;
          if (mp < cnt && t <= 30) {
            int fxpw = k_flist[secS[r] + mp];
            int fxv = fxpw - 30;
            bool keep = (t * t + fxv * fxv) <= 900;
            float re = nt == 0 ? accR0[rr] : accR1[rr];
            float im = nt == 0 ? accI0[rr] : accI1[rr];
            X2c[fxpw * 31 + t] = keep ? make_float2(re, im) : make_float2(0.f, 0.f);
          }
        }
    }
  } else {
    // ================= k0: W^ precompute (bf16), separable 3x3 twiddles =================
    const int bid2 = (int)blockIdx.x - 1024;
    const int fxp = bid2 >> 4;  // 0..60
    const int ig = bid2 & 15;
    const int il = tid & 3;
    const int o = ((tid >> 5) << 3) | ((tid >> 2) & 7);
    const int i = ig * 4 + il;
    const int op = (o + 32) & 63;
    const float* wp = w + (size_t)(op * 64 + i) * 9;
    float w9[9];
#pragma unroll
    for (int k = 0; k < 9; ++k) w9[k] = wp[k];

    const float fx = (float)(fxp - 30);
    float sn, cs;
    __sincosf(fx * PI2_128, &sn, &cs);
    const float e1x = cs, e1y = -sn;
    const float e2x = e1x * e1x - e1y * e1y, e2y = 2.f * e1x * e1y;
    float rxr[3], rxi[3];
#pragma unroll
    for (int ky = 0; ky < 3; ++ky) {
      rxr[ky] = w9[ky * 3] + w9[ky * 3 + 1] * e1x + w9[ky * 3 + 2] * e2x;
      rxi[ky] = w9[ky * 3 + 1] * e1y + w9[ky * 3 + 2] * e2y;
    }
    float pyx = 1.f, pyy = 0.f;
    const float stx = 0.9987954562f, sty = -0.04906767433f;
    unsigned* Wb = Wt + (size_t)(fxp * 31) * 4096 + (o >> 3) * 512 + (i >> 4) * 128 +
                   (((i >> 2) & 3) * 8 + (o & 7)) * 4 + (i & 3);
    for (int fy = 0; fy < 31; ++fy) {
      float p2x = pyx * pyx - pyy * pyy, p2y = 2.f * pyx * pyy;
      float Wre = rxr[0] + (rxr[1] * pyx - rxi[1] * pyy) + (rxr[2] * p2x - rxi[2] * p2y);
      float Wim = rxi[0] + (rxr[1] * pyy + rxi[1] * pyx) + (rxr[2] * p2y + rxi[2] * p2x);
      Wb[(size_t)fy * 4096] = bf16_rne(Wre) | (bf16_rne(Wim) << 16);
      float nx = pyx * stx - pyy * sty;
      pyy = pyx * sty + pyy * stx;
      pyx = nx;
    }
  }
}

// ---------------- KTX: X2[bi][f2] -> X2T[f2][i*16+b]  (64x64 float2 LDS tiles) ------
__global__ __launch_bounds__(256) void ktx(const float2* __restrict__ X2,
                                           float2* __restrict__ X2T) {
  __shared__ __align__(16) float2 Ld[4096];
  const int tid = threadIdx.x;
  const int tf = blockIdx.x % 30;  // f2 tile
  const int tc = blockIdx.x / 30;  // out-col tile: i0 = tc*4
  const int f2_0 = tf * 64;
  const int lo = tid & 63, hi = tid >> 6;
#pragma unroll
  for (int k = 0; k < 16; ++k) {
    int c = k * 4 + hi;  // local out-col: c = (i-i0)*16 + b
    int bi = (c & 15) * 64 + tc * 4 + (c >> 4);
    int f2 = f2_0 + lo;
    float2 v = (f2 < NF) ? X2[(size_t)bi * NF + f2] : make_float2(0.f, 0.f);
    Ld[(c << 6) | (lo ^ c)] = v;  // XOR-swizzled: conflict-free both phases
  }
  __syncthreads();
#pragma unroll
  for (int k = 0; k < 16; ++k) {
    int fr = k * 4 + hi;
    int f2 = f2_0 + fr;
    if (f2 < NF) X2T[(size_t)f2 * 1024 + tc * 64 + lo] = Ld[(lo << 6) | (fr ^ lo)];
  }
}

// ---------------- K3: per-frequency channel mix via MFMA (bf16, X split hi/lo) ----
__global__ __launch_bounds__(256) void k3_mfma(const float* X2T,
                                               const unsigned* __restrict__ WtB,
                                               float* F) {
  // bijective XCD-chunked blockIdx swizzle (m204 form)
  const int nwg = (int)gridDim.x;
  const int orig = (int)blockIdx.x;
  const int xcd = orig & 7;
  const int q = nwg >> 3, r = nwg & 7;
  const int blk = (xcd < r ? xcd * (q + 1) : r * (q + 1) + (xcd - r) * q) + (orig >> 3);

  const int tid = (int)threadIdx.x;
  const int wv = tid >> 6;
  const int g = blk * 4 + wv;
  const int f2v = g >> 1;
  const bool valid = f2v < NF;
  const int f2 = valid ? f2v : NF - 1;  // clamp keeps reads in the block's own rows
  const int half = g & 1;
  const int lane = tid & 63;
  const int m = lane & 15;   // A-row (output batch) == B-col-within-tile
  const int lg = lane >> 4;  // k lane-group
  const int bs = (m + 8) & 15;
  const int co = m & 1;      // re/im column parity

  // ---- A: gather X2T row f2 (coalesced); i = ks*16 + lg*4 + t ----
  float2 xv[4][4];
  const float2* Xc = (const float2*)X2T;
#pragma unroll
  for (int ks = 0; ks < 4; ++ks)
#pragma unroll
    for (int t = 0; t < 4; ++t)
      xv[ks][t] = Xc[(size_t)f2 * 1024 + (ks * 16 + lg * 4 + t) * 16 + bs];

  __syncthreads();  // all waves done reading their rows before any in-place store

  unsigned ahi[4][4], alo[4][4];
#pragma unroll
  for (int ks = 0; ks < 4; ++ks) {
#pragma unroll
    for (int t = 0; t < 4; ++t) {
      float xr = xv[ks][t].x, xi = xv[ks][t].y;
      unsigned hr = bf16_rne(xr), hi2 = bf16_rne(xi);
      float lr = xr - __uint_as_float(hr << 16);
      float li = xi - __uint_as_float(hi2 << 16);
      ahi[ks][t] = hr | (hi2 << 16);
      alo[ks][t] = bf16_rne(lr) | (bf16_rne(li) << 16);
    }
  }

  f32x4 acc[4];
#pragma unroll
  for (int nt = 0; nt < 4; ++nt) acc[nt] = {0.f, 0.f, 0.f, 0.f};

  const unsigned* Wb =
      WtB + (size_t)f2 * 4096 + half * 2048 + (lg * 8 + (m >> 1)) * 4;
#pragma unroll
  for (int ks = 0; ks < 4; ++ks) {
    bf16x8 bfr[4];
#pragma unroll
    for (int nt = 0; nt < 4; ++nt) {
      uint4 wq = *(const uint4*)(Wb + nt * 512 + ks * 128);
      unsigned b0, b1, b2, b3;
      if (co) {  // odd col: (Wi, Wr) = rot16(w)
        b0 = (wq.x >> 16) | (wq.x << 16);
        b1 = (wq.y >> 16) | (wq.y << 16);
        b2 = (wq.z >> 16) | (wq.z << 16);
        b3 = (wq.w >> 16) | (wq.w << 16);
      } else {   // even col: (Wr, -Wi) = w ^ signbit(hi)
        b0 = wq.x ^ 0x80000000u;
        b1 = wq.y ^ 0x80000000u;
        b2 = wq.z ^ 0x80000000u;
        b3 = wq.w ^ 0x80000000u;
      }
      bfr[nt] = mk_bf16x8(b0, b1, b2, b3);
    }
    bf16x8 ah = mk_bf16x8(ahi[ks][0], ahi[ks][1], ahi[ks][2], ahi[ks][3]);
    bf16x8 al = mk_bf16x8(alo[ks][0], alo[ks][1], alo[ks][2], alo[ks][3]);
#pragma unroll
    for (int nt = 0; nt < 4; ++nt)
      acc[nt] = __builtin_amdgcn_mfma_f32_16x16x32_bf16(ah, bfr[nt], acc[nt], 0, 0, 0);
#pragma unroll
    for (int nt = 0; nt < 4; ++nt)
      acc[nt] = __builtin_amdgcn_mfma_f32_16x16x32_bf16(al, bfr[nt], acc[nt], 0, 0, 0);
  }

  if (valid) {
    float* Fo = F + (size_t)f2 * 2048 + half * 64 + m;
#pragma unroll
    for (int nt = 0; nt < 4; ++nt)
#pragma unroll
      for (int rr = 0; rr < 4; ++rr)
        Fo[(lg * 4 + rr) * 128 + nt * 16] = acc[nt][rr];
  }
}

// ---------------- KTF: F[f2][bo] -> FT[bo][f2]  (64x64 float2 LDS tiles) -----------
__global__ __launch_bounds__(256) void ktf(const float2* __restrict__ F2,
                                           float2* __restrict__ FT) {
  __shared__ __align__(16) float2 Ld[4096];
  const int tid = threadIdx.x;
  const int tf = blockIdx.x % 30;
  const int tc = blockIdx.x / 30;
  const int f2_0 = tf * 64, c0 = tc * 64;
  const int lo = tid & 63, hi = tid >> 6;
#pragma unroll
  for (int k = 0; k < 16; ++k) {
    int fr = k * 4 + hi;
    int f2 = f2_0 + fr;
    float2 v = (f2 < NF) ? F2[(size_t)f2 * 1024 + c0 + lo] : make_float2(0.f, 0.f);
    Ld[(fr << 6) | (lo ^ fr)] = v;
  }
  __syncthreads();
#pragma unroll
  for (int k = 0; k < 16; ++k) {
    int cc = k * 4 + hi;
    int f2 = f2_0 + lo;
    if (f2 < NF) FT[(size_t)(c0 + cc) * NF + f2] = Ld[(lo << 6) | (cc ^ lo)];
  }
}

// ---------------- K45: inverse (radix-4 fold in x) + MFMA inverse-y + bias ----------
__global__ __launch_bounds__(256) void k45_out(const float* __restrict__ FT,
                                               const float* __restrict__ bias,
                                               float* __restrict__ out) {
  __shared__ __align__(16) float2 tw[128];  // e^{+2pi i m/128}
  __shared__ __align__(16) float U[61 * 132];
  __shared__ __align__(16) float TF[3904];  // Fl staging (phase 1 only)
  const int b = blockIdx.x >> 6;
  const int o = blockIdx.x & 63;
  const int tid = threadIdx.x;
  float2* Fl = (float2*)TF;
  // FT layout [bo][NF] -> contiguous row load.
  const float2* Fc = (const float2*)FT + (size_t)(b * 64 + o) * NF;
  if (tid < 128) {
    float sv, cv;
    __sincosf((float)tid * PI2_128, &sv, &cv);
    tw[tid] = make_float2(cv, sv);
  }
  for (int j = tid; j < NF; j += 256) Fl[j] = Fc[j];
  __syncthreads();

  // Phase 1: inverse-x with output fold H(x+32k) = sum_r i^{rk} S_r
  {
    const int fy = tid & 31;
    const int xg = tid >> 3 >> 2;  // tid>>5: 0..7
    if (fy < 31) {
      float Sr[4][4] = {{0.f}}, Si[4][4] = {{0.f}};  // [r][j]
      float pr[4], pi[4], cr[4], ci[4];
#pragma unroll
      for (int j = 0; j < 4; ++j) {
        int xj = 4 * xg + j;
        float2 st = tw[xj];
        cr[j] = st.x;
        ci[j] = st.y;
        float2 p0 = tw[(-30 * xj) & 127];
        pr[j] = p0.x;
        pi[j] = p0.y;
      }
      const float2* Frow = Fl + fy;
      for (int f4 = 0; f4 < 60; f4 += 4) {
#pragma unroll
        for (int ss = 0; ss < 4; ++ss) {
          const int r = (ss + 2) & 3;  // fxp class pattern 2,3,0,1
          float2 fv = Frow[(f4 + ss) * 31];
#pragma unroll
          for (int j = 0; j < 4; ++j) {
            Sr[r][j] += fv.x * pr[j] - fv.y * pi[j];
            Si[r][j] += fv.x * pi[j] + fv.y * pr[j];
            float np = pr[j] * cr[j] - pi[j] * ci[j];
            pi[j] = pi[j] * cr[j] + pr[j] * ci[j];
            pr[j] = np;
          }
        }
      }
      {  // fxp = 60, class 2
        float2 fv = Frow[60 * 31];
#pragma unroll
        for (int j = 0; j < 4; ++j) {
          Sr[2][j] += fv.x * pr[j] - fv.y * pi[j];
          Si[2][j] += fv.x * pi[j] + fv.y * pr[j];
        }
      }
#pragma unroll
      for (int j = 0; j < 4; ++j) {
        int xj = 4 * xg + j;
        float Er = Sr[0][j] + Sr[2][j], Ei = Si[0][j] + Si[2][j];
        float Fr = Sr[0][j] - Sr[2][j], Fi = Si[0][j] - Si[2][j];
        float Gr = Sr[1][j] + Sr[3][j], Gi = Si[1][j] + Si[3][j];
        float Hr = Sr[1][j] - Sr[3][j], Hi = Si[1][j] - Si[3][j];
        U[fy * 132 + xj] = Er + Gr;
        U[fy * 132 + xj + 32] = Fr - Hi;   // F4 + iH
        U[fy * 132 + xj + 64] = Er - Gr;
        U[fy * 132 + xj + 96] = Fr + Hi;   // F4 - iH
        if (fy >= 1) {
          U[(30 + fy) * 132 + xj] = Ei + Gi;
          U[(30 + fy) * 132 + xj + 32] = Fi + Hr;
          U[(30 + fy) * 132 + xj + 64] = Ei - Gi;
          U[(30 + fy) * 132 + xj + 96] = Fi - Hr;
        }
      }
    }
  }
  __syncthreads();

  // Phase 2 (MFMA): out rows y (M=64) x cols x (N=128). P = even-c GEMM, Q = odd-c GEMM,
  // K=32 (one MFMA step). A = T on-the-fly from tw; B = U from LDS. 3-term bf16 hi/lo split.
  {
    const int wv = tid >> 6;       // wave -> y-tile
    const int lane = tid & 63;
    const int mm = lane & 15;
    const int kg = lane >> 4;      // k-group
    const int yA = wv * 16 + mm;   // A-frag row (y)
    const float sc1 = 1.f / 16384.f;

    unsigned aPh[4], aPl[4], aQh[4], aQl[4];
#pragma unroll
    for (int pr = 0; pr < 4; ++pr) {
      unsigned hP[2], lP[2], hQ[2], lQ[2];
#pragma unroll
      for (int h2 = 0; h2 < 2; ++h2) {
        int s = pr * 2 + h2;
        int ce = 16 * kg + 2 * s;  // even c for P
        int co = ce + 1;           // odd c for Q
        float vP, vQ;
        if (ce == 0) vP = sc1;
        else if (ce <= 30) vP = 2.f * sc1 * tw[(ce * yA) & 127].x;
        else if (ce <= 60) vP = -2.f * sc1 * tw[((ce - 30) * yA) & 127].y;
        else vP = 0.f;
        if (co <= 30) vQ = 2.f * sc1 * tw[(co * yA) & 127].x;
        else if (co <= 59) vQ = -2.f * sc1 * tw[((co - 30) * yA) & 127].y;
        else vQ = 0.f;
        unsigned h = bf16_rne(vP);
        hP[h2] = h;
        lP[h2] = bf16_rne(vP - __uint_as_float(h << 16));
        h = bf16_rne(vQ);
        hQ[h2] = h;
        lQ[h2] = bf16_rne(vQ - __uint_as_float(h << 16));
      }
      aPh[pr] = hP[0] | (hP[1] << 16);
      aPl[pr] = lP[0] | (lP[1] << 16);
      aQh[pr] = hQ[0] | (hQ[1] << 16);
      aQl[pr] = lQ[0] | (lQ[1] << 16);
    }
    const bf16x8 APh = mk_bf16x8(aPh[0], aPh[1], aPh[2], aPh[3]);
    const bf16x8 APl = mk_bf16x8(aPl[0], aPl[1], aPl[2], aPl[3]);
    const bf16x8 AQh = mk_bf16x8(aQh[0], aQh[1], aQh[2], aQh[3]);
    const bf16x8 AQl = mk_bf16x8(aQl[0], aQl[1], aQl[2], aQl[3]);

    const float bo_ = bias[o];
    float* op = out + (size_t)(b * 64 + o) * 16384;
#pragma unroll
    for (int n = 0; n < 8; ++n) {
      unsigned uph[4], upl[4], uqh[4], uql[4];
#pragma unroll
      for (int pr = 0; pr < 4; ++pr) {
        unsigned h0[2], l0[2], h1[2], l1[2];
#pragma unroll
        for (int h2 = 0; h2 < 2; ++h2) {
          int s = pr * 2 + h2;
          int ce = 16 * kg + 2 * s;
          int rP = ce > 60 ? 60 : ce;            // clamped (A slot is 0 there)
          int rQ = (ce + 1) > 60 ? 60 : ce + 1;  // clamped
          float uP = U[rP * 132 + n * 16 + mm];
          float uQ = U[rQ * 132 + n * 16 + mm];
          unsigned h = bf16_rne(uP);
          h0[h2] = h;
          l0[h2] = bf16_rne(uP - __uint_as_float(h << 16));
          h = bf16_rne(uQ);
          h1[h2] = h;
          l1[h2] = bf16_rne(uQ - __uint_as_float(h << 16));
        }
        uph[pr] = h0[0] | (h0[1] << 16);
        upl[pr] = l0[0] | (l0[1] << 16);
        uqh[pr] = h1[0] | (h1[1] << 16);
        uql[pr] = l1[0] | (l1[1] << 16);
      }
      bf16x8 UPh = mk_bf16x8(uph[0], uph[1], uph[2], uph[3]);
      bf16x8 UPl = mk_bf16x8(upl[0], upl[1], upl[2], upl[3]);
      bf16x8 UQh = mk_bf16x8(uqh[0], uqh[1], uqh[2], uqh[3]);
      bf16x8 UQl = mk_bf16x8(uql[0], uql[1], uql[2], uql[3]);
      f32x4 accP = {0.f, 0.f, 0.f, 0.f}, accQ = {0.f, 0.f, 0.f, 0.f};
      accP = __builtin_amdgcn_mfma_f32_16x16x32_bf16(APh, UPh, accP, 0, 0, 0);
      accP = __builtin_amdgcn_mfma_f32_16x16x32_bf16(APh, UPl, accP, 0, 0, 0);
      accP = __builtin_amdgcn_mfma_f32_16x16x32_bf16(APl, UPh, accP, 0, 0, 0);
      accQ = __builtin_amdgcn_mfma_f32_16x16x32_bf16(AQh, UQh, accQ, 0, 0, 0);
      accQ = __builtin_amdgcn_mfma_f32_16x16x32_bf16(AQh, UQl, accQ, 0, 0, 0);
      accQ = __builtin_amdgcn_mfma_f32_16x16x32_bf16(AQl, UQh, accQ, 0, 0, 0);
#pragma unroll
      for (int rr = 0; rr < 4; ++rr) {
        int y = wv * 16 + kg * 4 + rr;  // D row = (lane>>4)*4 + reg
        float p = accP[rr], qq = accQ[rr];
        op[y * 128 + n * 16 + mm] = p + qq + bo_;
        op[(y + 64) * 128 + n * 16 + mm] = p - qq + bo_;
      }
    }
  }
}

extern "C" void kernel_launch(void* const* d_in, const int* in_sizes, int n_in,
                              void* d_out, int out_size, void* d_ws, size_t ws_size,
                              hipStream_t stream) {
  (void)in_sizes; (void)n_in; (void)out_size; (void)ws_size;
  const float* x = (const float*)d_in[0];
  const float* w = (const float*)d_in[1];
  const float* bias = (const float*)d_in[2];
  float* out = (float*)d_out;

  unsigned* Wt = (unsigned*)d_ws;
  float* A = (float*)d_ws + 7745536;    // X2, later FT
  float* B = (float*)d_ws + 11618304;   // X2T, in-place F

  k012<<<2000, 256, 0, stream>>>(x, A, w, Wt);
  ktx<<<480, 256, 0, stream>>>((const float2*)A, (float2*)B);
  k3_mfma<<<946, 256, 0, stream>>>(B, Wt, B);
  ktf<<<480, 256, 0, stream>>>((const float2*)B, (float2*)A);
  k45_out<<<1024, 256, 0, stream>>>(A, bias, out);
}